// Round 3
// baseline (861.740 us; speedup 1.0000x reference)
//
#include <hip/hip_runtime.h>
#include <cstdint>
#include <cstddef>

// ============================================================================
// SSD forward (image 7 only) + NMS, all fp32.
// R2: R1's fast conv structure (de-interleaved even/odd LDS planes, double
// buffering, 1 barrier/stage) but with R0's EXACT fp accumulation order
// restored: conv3 KSPLIT=1 (bias in-kernel), conv4 KSPLIT=4 (64-ci chunks)
// with R0's combine ((p0+p1)+p2)+p3 + b. R1's KSPLIT reshuffle flipped one
// borderline sort/NMS decision (absmax 0.51).
// ============================================================================

// ---------------- weight repack: w[co][ci][3][3] -> wr[(ci*9+tap)*COUT+co] ---
__global__ __launch_bounds__(256) void k_repack_w(const float* __restrict__ w,
                                                  float* __restrict__ wr,
                                                  int CIN, int COUT, int total) {
  int idx = blockIdx.x * 256 + threadIdx.x;
  if (idx >= total) return;
  int co = idx % COUT;
  int r  = idx / COUT;
  int ci = r / 9;
  int tap = r % 9;
  wr[idx] = w[(co * CIN + ci) * 9 + tap];
}

// head weights: wh[(tap*25+o)*256+ci], o<4 = reg rows, o>=4 = cls rows
__global__ __launch_bounds__(256) void k_repack_head(const float* __restrict__ regw,
                                                     const float* __restrict__ clsw,
                                                     float* __restrict__ wh) {
  int idx = blockIdx.x * 256 + threadIdx.x;
  if (idx >= 9 * 25 * 256) return;
  int ci = idx & 255;
  int r  = idx >> 8;
  int tap = r / 25;
  int o   = r % 25;
  wh[idx] = (o < 4) ? regw[(o * 256 + ci) * 9 + tap]
                    : clsw[((o - 4) * 256 + ci) * 9 + tap];
}

// ---------------- conv1: 3->64, 512->256, stride 2, co-split by blockIdx.z ---
__global__ __launch_bounds__(256) void k_conv1(const float* __restrict__ x,
                                               const float* __restrict__ w,
                                               const float* __restrict__ b,
                                               float* __restrict__ out) {
  __shared__ float in_t[3][33][33];
  const int tx = threadIdx.x, ty = threadIdx.y;
  const int tid = ty * 16 + tx;
  const int ox0 = blockIdx.x * 16, oy0 = blockIdx.y * 16;
  const int co0 = blockIdx.z * 32;
  for (int idx = tid; idx < 3 * 33 * 33; idx += 256) {
    int ci = idx / 1089, rem = idx % 1089;
    int r = rem / 33, c = rem % 33;
    int iy = oy0 * 2 + r, ix = ox0 * 2 + c;
    float v = 0.f;
    if (iy < 512 && ix < 512) v = x[(size_t)ci * 262144 + iy * 512 + ix];
    in_t[ci][r][c] = v;
  }
  __syncthreads();
  float rin[27];
#pragma unroll
  for (int ci = 0; ci < 3; ++ci)
#pragma unroll
    for (int kh = 0; kh < 3; ++kh)
#pragma unroll
      for (int kw = 0; kw < 3; ++kw)
        rin[ci * 9 + kh * 3 + kw] = in_t[ci][2 * ty + kh][2 * tx + kw];
  const int oy = oy0 + ty, ox = ox0 + tx;
  for (int co = co0; co < co0 + 32; ++co) {  // co uniform -> weights via s_load
    float a = 0.f;
#pragma unroll
    for (int k = 0; k < 27; ++k) a = fmaf(w[co * 27 + k], rin[k], a);
    out[(size_t)co * 65536 + oy * 256 + ox] = fmaxf(a + b[co], 0.f);
  }
}

// ---------------- generic stride-2 3x3 conv, SAME(pad lo 0 hi 1) -------------
// 256 thr = 4 co-groups (wave-uniform cout via readfirstlane) x 64 lanes.
// Lane lp -> output position (py=lp/SW, px=lp%SW); SH*SW == 64.
// LDS: per buffer, EV plane (even input cols) + OD plane (odd input cols),
// each CIT*IH rows of PADW floats -> stride-2 conv reads become stride-1.
// Double-buffered, one __syncthreads per ci-stage.
// Per-output accumulation order: (ci,kh,kw) lexicographic — matches R0.
template <int CIN, int COUT, int HIN, int WIN, int SH, int SW, int COPT,
          int CIT, int KSPLIT>
__global__ __launch_bounds__(256) void conv_s2(const float* __restrict__ in,
                                               const float* __restrict__ wr,
                                               const float* __restrict__ bias,
                                               float* __restrict__ out) {
  constexpr int HOUT = HIN / 2, WOUT = WIN / 2;
  constexpr int IH = SH * 2 + 1, IW = SW * 2 + 1;
  constexpr int COT = 4 * COPT;
  constexpr int PADW = (SW == 16) ? 19 : (SW + 1);
  constexpr int ODOFF = CIT * IH * PADW;
  constexpr int BUFSZ = 2 * ODOFF;
  constexpr int TOT = CIT * IH * IW;
  constexpr int NLD = (TOT + 255) / 256;
  static_assert(SH * SW == 64, "one position per lane");
  __shared__ float lds[2][BUFSZ];

  const int tid = threadIdx.x;
  const int gu  = __builtin_amdgcn_readfirstlane(tid >> 6);
  const int lp  = tid & 63;
  const int py  = lp / SW, px = lp % SW;

  constexpr int ntx = WOUT / SW;
  const int bx = blockIdx.x % ntx, by = blockIdx.x / ntx;
  const int ox0 = bx * SW, oy0 = by * SH;
  const int co_blk = blockIdx.y * COT;
  const int cobase = co_blk + gu * COPT;
  const int ci_begin = (KSPLIT > 1) ? blockIdx.z * (CIN / KSPLIT) : 0;
  constexpr int NST = (CIN / KSPLIT) / CIT;

  // ---- precompute per-l staging offsets (stage-invariant) ----
  int goff[NLD], loff[NLD];
  unsigned vmask = 0;
#pragma unroll
  for (int l = 0; l < NLD; ++l) {
    int idx = tid + l * 256;
    if (idx < TOT) {
      int ci = idx / (IH * IW), rem = idx % (IH * IW);
      int r = rem / IW, c = rem % IW;
      int iy = oy0 * 2 + r, ix = ox0 * 2 + c;
      bool ok = (iy < HIN) && (ix < WIN);
      goff[l] = ok ? (ci * (HIN * WIN) + iy * WIN + ix) : 0;
      loff[l] = (c & 1) * ODOFF + (ci * IH + r) * PADW + (c >> 1);
      if (ok) vmask |= 1u << l;
    } else {
      goff[l] = 0;
      loff[l] = ODOFF + SW;  // unused OD pad slot
    }
  }

  float pre[NLD];
  auto load_stage = [&](int cib) {
    const float* src = in + (size_t)cib * (HIN * WIN);
#pragma unroll
    for (int l = 0; l < NLD; ++l) {
      float v = src[goff[l]];
      pre[l] = ((vmask >> l) & 1u) ? v : 0.f;
    }
  };
  auto store_stage = [&](int buf) {
#pragma unroll
    for (int l = 0; l < NLD; ++l) lds[buf][loff[l]] = pre[l];
  };

  float acc[COPT] = {};

  load_stage(ci_begin);
  store_stage(0);

  for (int st = 0; st < NST; ++st) {
    __syncthreads();
    if (st + 1 < NST) load_stage(ci_begin + (st + 1) * CIT);
    const float* Lb = &lds[st & 1][0];
    const int cib = ci_begin + st * CIT;
    for (int ci = 0; ci < CIT; ++ci) {
#pragma unroll
      for (int kh = 0; kh < 3; ++kh) {
        const int row = (ci * IH + 2 * py + kh) * PADW;
        float e0 = Lb[row + px];
        float o0 = Lb[ODOFF + row + px];
        float e1 = Lb[row + px + 1];
        const float* wp =
            wr + ((size_t)(cib + ci) * 9 + kh * 3) * COUT + cobase;
#pragma unroll
        for (int c = 0; c < COPT; ++c) acc[c] = fmaf(e0, wp[c], acc[c]);
#pragma unroll
        for (int c = 0; c < COPT; ++c) acc[c] = fmaf(o0, wp[COUT + c], acc[c]);
#pragma unroll
        for (int c = 0; c < COPT; ++c) acc[c] = fmaf(e1, wp[2 * COUT + c], acc[c]);
      }
    }
    if (st + 1 < NST) store_stage((st + 1) & 1);
  }

  const int oy = oy0 + py, ox = ox0 + px;
#pragma unroll
  for (int c = 0; c < COPT; ++c) {
    int co = cobase + c;
    if constexpr (KSPLIT > 1) {
      out[((size_t)blockIdx.z * COUT + co) * (HOUT * WOUT) + oy * WOUT + ox] =
          acc[c];
    } else {
      out[(size_t)co * (HOUT * WOUT) + oy * WOUT + ox] =
          fmaxf(acc[c] + bias[co], 0.f);
    }
  }
}

// ---------------- combine conv4 K-split partials + bias + relu, write NHWC ---
// EXACT R0 semantics: v = ((p0+p1)+p2)+p3; out = max(v+b, 0)
__global__ __launch_bounds__(256) void k_combine(const float* __restrict__ part,
                                                 const float* __restrict__ b,
                                                 float* __restrict__ h4t) {
  int co = blockIdx.x;  // 0..255
  float bb = b[co];
  for (int k2 = 0; k2 < 4; ++k2) {
    int pos = threadIdx.x + k2 * 256;
    float v = part[(size_t)(0 * 256 + co) * 1024 + pos] +
              part[(size_t)(1 * 256 + co) * 1024 + pos] +
              part[(size_t)(2 * 256 + co) * 1024 + pos] +
              part[(size_t)(3 * 256 + co) * 1024 + pos];
    h4t[(size_t)pos * 256 + co] = fmaxf(v + bb, 0.f);
  }
}

// ---------------- head: reg(4)+cls(21) stride-1 conv + softmax/max/argmax ----
__global__ __launch_bounds__(256) void k_head(const float* __restrict__ h4t,
                                              const float* __restrict__ wh,
                                              const float* __restrict__ regb,
                                              const float* __restrict__ clsb,
                                              float* __restrict__ locs,
                                              float* __restrict__ confs,
                                              float* __restrict__ scores,
                                              float* __restrict__ labelsF) {
  const int pos = blockIdx.x;
  const int py = pos >> 5, px = pos & 31;
  const int t = threadIdx.x;
  float part[25] = {};
#pragma unroll
  for (int kh = 0; kh < 3; ++kh) {
    int iy = py + kh - 1;
    if (iy < 0 || iy > 31) continue;  // block-uniform
#pragma unroll
    for (int kw = 0; kw < 3; ++kw) {
      int ix = px + kw - 1;
      if (ix < 0 || ix > 31) continue;
      int tap = kh * 3 + kw;
      float v = h4t[(size_t)(iy * 32 + ix) * 256 + t];
      const float* wp = wh + (size_t)tap * 25 * 256 + t;
#pragma unroll
      for (int o = 0; o < 25; ++o)
        part[o] = fmaf(v, wp[(size_t)o * 256], part[o]);
    }
  }
#pragma unroll
  for (int o = 0; o < 25; ++o) {
#pragma unroll
    for (int d = 1; d < 64; d <<= 1) part[o] += __shfl_xor(part[o], d);
  }
  __shared__ float red[4][25];
  __shared__ float yv[25];
  const int wv = t >> 6, ln = t & 63;
  if (ln == 0) {
#pragma unroll
    for (int o = 0; o < 25; ++o) red[wv][o] = part[o];
  }
  __syncthreads();
  if (t < 25) {
    float y = red[0][t] + red[1][t] + red[2][t] + red[3][t];
    y += (t < 4) ? regb[t] : clsb[t - 4];
    if (t < 4) locs[(size_t)pos * 4 + t] = y;
    else       confs[(size_t)pos * 21 + (t - 4)] = y;
    yv[t] = y;
  }
  __syncthreads();
  if (t == 0) {
    float m = yv[4];
    int lab = 0;
    for (int j = 1; j < 21; ++j)
      if (yv[4 + j] > m) { m = yv[4 + j]; lab = j; }  // first-max semantics
    float s = 0.f;
    for (int j = 0; j < 21; ++j) s += expf(yv[4 + j] - m);
    scores[pos] = 1.f / s;   // max softmax prob
    labelsF[pos] = (float)lab;
  }
}

// ---------------- stable descending bitonic sort of 1024 scores --------------
__global__ __launch_bounds__(512) void k_sort(const float* __restrict__ scores,
                                              const float* __restrict__ locs,
                                              int* __restrict__ order,
                                              float* __restrict__ ssc,
                                              float* __restrict__ bsrt,
                                              unsigned long long* __restrict__ vbits) {
  __shared__ float sk[1024];
  __shared__ int   si[1024];
  const int t = threadIdx.x;
  sk[t] = scores[t];           si[t] = t;
  sk[t + 512] = scores[t + 512]; si[t + 512] = t + 512;
  for (int k = 2; k <= 1024; k <<= 1) {
    for (int j = k >> 1; j > 0; j >>= 1) {
      __syncthreads();
      int i1 = ((t / j) * (2 * j)) + (t % j);
      int i2 = i1 + j;
      bool up = (i1 & k) == 0;
      float sa = sk[i1], sb = sk[i2];
      int ia = si[i1], ib = si[i2];
      bool b_before_a = (sb > sa) || (sb == sa && ib < ia);
      bool a_before_b = (sa > sb) || (sa == sb && ia < ib);
      bool sw = up ? b_before_a : a_before_b;
      if (sw) { sk[i1] = sb; sk[i2] = sa; si[i1] = ib; si[i2] = ia; }
    }
  }
  __syncthreads();
  for (int i = t; i < 1024; i += 512) {
    int oi = si[i];
    order[i] = oi;
    ssc[i] = sk[i];
    ((float4*)bsrt)[i] = ((const float4*)locs)[oi];
  }
  if (t < 16) {  // validity bits (score > SCORE_THR), sorted order
    unsigned long long w = 0;
    for (int b2 = 0; b2 < 64; ++b2)
      if (sk[t * 64 + b2] > 0.04f) w |= (1ull << b2);
    vbits[t] = w;
  }
}

// ---------------- pairwise IoU suppression bitmask (1024x1024 bits) ----------
__global__ __launch_bounds__(256) void k_mask(const float* __restrict__ bsrt,
                                              unsigned long long* __restrict__ mask) {
  __shared__ float4 sb[1024];
  const int t = threadIdx.x;
  for (int idx = t; idx < 1024; idx += 256)
    sb[idx] = ((const float4*)bsrt)[idx];
  __syncthreads();
  const int i = blockIdx.x * 16 + (t & 15);
  const int w = t >> 4;
  float4 bi = sb[i];
  float ai = (bi.z - bi.x) * (bi.w - bi.y);
  unsigned long long bits = 0;
  for (int jj = 0; jj < 64; ++jj) {
    float4 bj = sb[w * 64 + jj];
    float aj = (bj.z - bj.x) * (bj.w - bj.y);
    float ltx = fmaxf(bi.x, bj.x), lty = fmaxf(bi.y, bj.y);
    float rbx = fminf(bi.z, bj.z), rby = fminf(bi.w, bj.w);
    float inter = fmaxf(rbx - ltx, 0.f) * fmaxf(rby - lty, 0.f);
    float uni = ai + aj - inter;
    float iou = inter / (uni + 1e-9f);
    if (iou > 0.5f) bits |= (1ull << jj);
  }
  mask[(size_t)i * 16 + w] = bits;
}

// ---------------- sequential greedy NMS scan (wave 0, LDS-staged halves) -----
__global__ __launch_bounds__(256) void k_scan(const unsigned long long* __restrict__ mask,
                                              const unsigned long long* __restrict__ vbits,
                                              unsigned long long* __restrict__ keepb) {
  __shared__ unsigned long long m_lds[512 * 16];  // exactly 64 KB
  const int t = threadIdx.x;
  unsigned long long keepm = 0, vw = 0;
  if (t < 16) vw = vbits[t];
  for (int ph = 0; ph < 2; ++ph) {
    __syncthreads();
    for (int idx = t; idx < 8192; idx += 256) m_lds[idx] = mask[ph * 8192 + idx];
    __syncthreads();
    if (t < 64) {
      for (int ii = 0; ii < 512; ++ii) {
        int i = ph * 512 + ii;
        unsigned long long row = (t < 16) ? m_lds[ii * 16 + t] : 0ull;
        bool hit = (row & keepm) != 0ull;
        bool sup = __any(hit);
        int wsel = i >> 6, bsel = i & 63;
        unsigned long long vword = __shfl(vw, wsel);
        bool vv = (vword >> bsel) & 1ull;
        bool kp = vv && !sup;
        if (kp && t == wsel) keepm |= (1ull << bsel);
      }
    }
  }
  __syncthreads();
  if (t < 16) keepb[t] = keepm;
}

// ---------------- final gather into d_out ------------------------------------
// layout: boxes[1024*4] | labels[1024] | scores[1024] | confs[1024*21]
__global__ __launch_bounds__(256) void k_gather(const unsigned long long* __restrict__ keepb,
                                                const int* __restrict__ order,
                                                const float* __restrict__ ssc,
                                                const float* __restrict__ locs,
                                                const float* __restrict__ confs,
                                                const float* __restrict__ labelsF,
                                                float* __restrict__ out) {
  int i = blockIdx.x * 256 + threadIdx.x;  // 0..1023
  bool k = (keepb[i >> 6] >> (i & 63)) & 1ull;
  int oi = order[i];
  float4 bx = k ? ((const float4*)locs)[oi] : make_float4(-1.f, -1.f, -1.f, -1.f);
  ((float4*)out)[i] = bx;
  out[4096 + i] = k ? labelsF[oi] : 0.f;
  out[5120 + i] = k ? ssc[i] : -1.f;
  float* oc = out + 6144 + (size_t)i * 21;
  const float* cc = confs + (size_t)oi * 21;
#pragma unroll
  for (int c = 0; c < 21; ++c) oc[c] = k ? cc[c] : -1.f;
}

// ============================================================================
extern "C" void kernel_launch(void* const* d_in, const int* in_sizes, int n_in,
                              void* d_out, int out_size, void* d_ws, size_t ws_size,
                              hipStream_t stream) {
  const float* x    = (const float*)d_in[0] + (size_t)7 * 3 * 512 * 512;  // image 7
  const float* w1   = (const float*)d_in[1];
  const float* b1   = (const float*)d_in[2];
  const float* w2   = (const float*)d_in[3];
  const float* b2   = (const float*)d_in[4];
  const float* w3   = (const float*)d_in[5];
  const float* b3   = (const float*)d_in[6];
  const float* w4   = (const float*)d_in[7];
  const float* b4   = (const float*)d_in[8];
  const float* regw = (const float*)d_in[9];
  const float* regb = (const float*)d_in[10];
  const float* clsw = (const float*)d_in[11];
  const float* clsb = (const float*)d_in[12];
  float* out = (float*)d_out;
  char* ws = (char*)d_ws;

  // region A (0..16.8MB): h1, then part4 + h4t
  float* h1    = (float*)(ws + 0);          // 16.8MB  (dead after conv2)
  float* part4 = (float*)(ws + 0);          // 4MB     (dead after combine)
  float* h4t   = (float*)(ws + 9437184);    // 1MB
  float* h2    = (float*)(ws + 16777216);   // 8.4MB   (dead after conv3)
  float* h3    = (float*)(ws + 25165824);   // 4.2MB
  float* wr2   = (float*)(ws + 29360128);
  float* wr3   = (float*)(ws + 29655040);
  float* wr4   = (float*)(ws + 30834688);
  float* wh    = (float*)(ws + 33193984);
  float* locs  = (float*)(ws + 33424384);
  float* confs = (float*)(ws + 33440768);
  float* scores  = (float*)(ws + 33526784);
  float* labelsF = (float*)(ws + 33530880);
  int*   order   = (int*)  (ws + 33534976);
  float* ssc     = (float*)(ws + 33539072);
  float* bsrt    = (float*)(ws + 33543168);
  unsigned long long* mask  = (unsigned long long*)(ws + 33559552);
  unsigned long long* vbits = (unsigned long long*)(ws + 33690624);
  unsigned long long* keepb = (unsigned long long*)(ws + 33690752);

  k_repack_w<<<288, 256, 0, stream>>>(w2, wr2, 64, 128, 73728);
  k_repack_w<<<1152, 256, 0, stream>>>(w3, wr3, 128, 256, 294912);
  k_repack_w<<<2304, 256, 0, stream>>>(w4, wr4, 256, 256, 589824);
  k_repack_head<<<225, 256, 0, stream>>>(regw, clsw, wh);

  k_conv1<<<dim3(16, 16, 2), dim3(16, 16), 0, stream>>>(x, w1, b1, h1);

  // conv2: 64->128, 256->128. 4x16 tiles => 256 sp-tiles x 4 co-blocks = 1024
  conv_s2<64, 128, 256, 256, 4, 16, 8, 8, 1>
      <<<dim3(256, 4, 1), 256, 0, stream>>>(h1, wr2, b2, h2);
  // conv3: 128->256, 128->64. KSPLIT=1 (R0 numerics). 64 sp x 8 co = 512
  conv_s2<128, 256, 128, 128, 8, 8, 8, 8, 1>
      <<<dim3(64, 8, 1), 256, 0, stream>>>(h2, wr3, b3, h3);
  // conv4: 256->256, 64->32. KSPLIT=4, 64-ci chunks (R0 numerics). 512 blocks
  conv_s2<256, 256, 64, 64, 8, 8, 8, 8, 4>
      <<<dim3(16, 8, 4), 256, 0, stream>>>(h3, wr4, (const float*)nullptr, part4);
  k_combine<<<256, 256, 0, stream>>>(part4, b4, h4t);

  k_head<<<1024, 256, 0, stream>>>(h4t, wh, regb, clsb, locs, confs, scores, labelsF);

  k_sort<<<1, 512, 0, stream>>>(scores, locs, order, ssc, bsrt, vbits);
  k_mask<<<64, 256, 0, stream>>>(bsrt, mask);
  k_scan<<<1, 256, 0, stream>>>(mask, vbits, keepb);
  k_gather<<<4, 256, 0, stream>>>(keepb, order, ssc, locs, confs, labelsF, out);
}

// Round 4
// 568.634 us; speedup vs baseline: 1.5155x; 1.5155x over previous
//
#include <hip/hip_runtime.h>
#include <cstdint>
#include <cstddef>

// ============================================================================
// SSD forward (image 7 only) + NMS, all fp32.
// R3: conv_s2 = R0's lean staging (direct global->LDS loop, 2 barriers/stage,
// low VGPR) + de-interleaved even/odd column planes (conflicts <=2-3-way,
// measured win) + CIT=32 (4x fewer barrier-locked stages). Accumulation order
// per output: (ci,kh,kw) lexicographic, conv4 KSPLIT=4 w/ R0 combine —
// exact R0 numerics (passed twice).
// ============================================================================

// ---------------- weight repack: w[co][ci][3][3] -> wr[(ci*9+tap)*COUT+co] ---
__global__ __launch_bounds__(256) void k_repack_w(const float* __restrict__ w,
                                                  float* __restrict__ wr,
                                                  int CIN, int COUT, int total) {
  int idx = blockIdx.x * 256 + threadIdx.x;
  if (idx >= total) return;
  int co = idx % COUT;
  int r  = idx / COUT;
  int ci = r / 9;
  int tap = r % 9;
  wr[idx] = w[(co * CIN + ci) * 9 + tap];
}

// head weights: wh[(tap*25+o)*256+ci], o<4 = reg rows, o>=4 = cls rows
__global__ __launch_bounds__(256) void k_repack_head(const float* __restrict__ regw,
                                                     const float* __restrict__ clsw,
                                                     float* __restrict__ wh) {
  int idx = blockIdx.x * 256 + threadIdx.x;
  if (idx >= 9 * 25 * 256) return;
  int ci = idx & 255;
  int r  = idx >> 8;
  int tap = r / 25;
  int o   = r % 25;
  wh[idx] = (o < 4) ? regw[(o * 256 + ci) * 9 + tap]
                    : clsw[((o - 4) * 256 + ci) * 9 + tap];
}

// ---------------- conv1: 3->64, 512->256, stride 2, co-split by blockIdx.z ---
__global__ __launch_bounds__(256) void k_conv1(const float* __restrict__ x,
                                               const float* __restrict__ w,
                                               const float* __restrict__ b,
                                               float* __restrict__ out) {
  __shared__ float in_t[3][33][33];
  const int tx = threadIdx.x, ty = threadIdx.y;
  const int tid = ty * 16 + tx;
  const int ox0 = blockIdx.x * 16, oy0 = blockIdx.y * 16;
  const int co0 = blockIdx.z * 32;
  for (int idx = tid; idx < 3 * 33 * 33; idx += 256) {
    int ci = idx / 1089, rem = idx % 1089;
    int r = rem / 33, c = rem % 33;
    int iy = oy0 * 2 + r, ix = ox0 * 2 + c;
    float v = 0.f;
    if (iy < 512 && ix < 512) v = x[(size_t)ci * 262144 + iy * 512 + ix];
    in_t[ci][r][c] = v;
  }
  __syncthreads();
  float rin[27];
#pragma unroll
  for (int ci = 0; ci < 3; ++ci)
#pragma unroll
    for (int kh = 0; kh < 3; ++kh)
#pragma unroll
      for (int kw = 0; kw < 3; ++kw)
        rin[ci * 9 + kh * 3 + kw] = in_t[ci][2 * ty + kh][2 * tx + kw];
  const int oy = oy0 + ty, ox = ox0 + tx;
  for (int co = co0; co < co0 + 32; ++co) {  // co uniform -> weights via s_load
    float a = 0.f;
#pragma unroll
    for (int k = 0; k < 27; ++k) a = fmaf(w[co * 27 + k], rin[k], a);
    out[(size_t)co * 65536 + oy * 256 + ox] = fmaxf(a + b[co], 0.f);
  }
}

// ---------------- generic stride-2 3x3 conv, SAME(pad lo 0 hi 1) -------------
// 256 thr = 4 co-groups (wave-uniform cout via readfirstlane) x 64 lanes.
// Lane lp -> output position (py=lp/SW, px=lp%SW); SH*SW == 64.
// LDS: EV plane (even input cols) + OD plane (odd input cols), row stride
// PADW -> stride-2 conv reads become stride-1 (<=2-3-way banks).
// Lean staging: direct global->LDS strided loop, 2 barriers/stage, CIT=32.
// Per-output accumulation order: (ci,kh,kw) lexicographic — matches R0.
template <int CIN, int COUT, int HIN, int WIN, int SH, int SW, int COPT,
          int CIT, int KSPLIT, int PADW>
__global__ __launch_bounds__(256) void conv_s2(const float* __restrict__ in,
                                               const float* __restrict__ wr,
                                               const float* __restrict__ bias,
                                               float* __restrict__ out) {
  constexpr int HOUT = HIN / 2, WOUT = WIN / 2;
  constexpr int IH = SH * 2 + 1, IW = SW * 2 + 1;
  constexpr int COT = 4 * COPT;
  constexpr int ODOFF = CIT * IH * PADW;
  constexpr int TOT = CIT * IH * IW;
  static_assert(SH * SW == 64, "one position per lane");
  __shared__ float lds[2 * ODOFF];

  const int tid = threadIdx.x;
  const int gu  = __builtin_amdgcn_readfirstlane(tid >> 6);
  const int lp  = tid & 63;
  const int py  = lp / SW, px = lp % SW;

  constexpr int ntx = WOUT / SW;
  const int bx = blockIdx.x % ntx, by = blockIdx.x / ntx;
  const int ox0 = bx * SW, oy0 = by * SH;
  const int co_blk = blockIdx.y * COT;
  const int cobase = co_blk + gu * COPT;
  const int ci_begin = (KSPLIT > 1) ? blockIdx.z * (CIN / KSPLIT) : 0;
  constexpr int NST = (CIN / KSPLIT) / CIT;

  float acc[COPT] = {};

  for (int st = 0; st < NST; ++st) {
    const int cib = ci_begin + st * CIT;
    if (st) __syncthreads();   // protect previous stage's reads
    // ---- lean staging: global -> LDS (de-interleaved planes) ----
    for (int idx = tid; idx < TOT; idx += 256) {
      int ci = idx / (IH * IW), rem = idx % (IH * IW);
      int r = rem / IW, c = rem % IW;
      int iy = oy0 * 2 + r, ix = ox0 * 2 + c;
      float v = 0.f;
      if (iy < HIN && ix < WIN)
        v = in[(size_t)(cib + ci) * HIN * WIN + iy * WIN + ix];
      lds[(c & 1) * ODOFF + (ci * IH + r) * PADW + (c >> 1)] = v;
    }
    __syncthreads();
    // ---- compute ----
    for (int ci = 0; ci < CIT; ++ci) {
#pragma unroll
      for (int kh = 0; kh < 3; ++kh) {
        const int row = (ci * IH + 2 * py + kh) * PADW;
        float e0 = lds[row + px];          // kw=0 : col 2px
        float o0 = lds[ODOFF + row + px];  // kw=1 : col 2px+1
        float e1 = lds[row + px + 1];      // kw=2 : col 2px+2
        const float* wp =
            wr + ((size_t)(cib + ci) * 9 + kh * 3) * COUT + cobase;
#pragma unroll
        for (int c = 0; c < COPT; ++c) acc[c] = fmaf(e0, wp[c], acc[c]);
#pragma unroll
        for (int c = 0; c < COPT; ++c) acc[c] = fmaf(o0, wp[COUT + c], acc[c]);
#pragma unroll
        for (int c = 0; c < COPT; ++c) acc[c] = fmaf(e1, wp[2 * COUT + c], acc[c]);
      }
    }
  }

  const int oy = oy0 + py, ox = ox0 + px;
#pragma unroll
  for (int c = 0; c < COPT; ++c) {
    int co = cobase + c;
    if constexpr (KSPLIT > 1) {
      out[((size_t)blockIdx.z * COUT + co) * (HOUT * WOUT) + oy * WOUT + ox] =
          acc[c];
    } else {
      out[(size_t)co * (HOUT * WOUT) + oy * WOUT + ox] =
          fmaxf(acc[c] + bias[co], 0.f);
    }
  }
}

// ---------------- combine conv4 K-split partials + bias + relu, write NHWC ---
// EXACT R0 semantics: v = ((p0+p1)+p2)+p3; out = max(v+b, 0)
__global__ __launch_bounds__(256) void k_combine(const float* __restrict__ part,
                                                 const float* __restrict__ b,
                                                 float* __restrict__ h4t) {
  int co = blockIdx.x;  // 0..255
  float bb = b[co];
  for (int k2 = 0; k2 < 4; ++k2) {
    int pos = threadIdx.x + k2 * 256;
    float v = part[(size_t)(0 * 256 + co) * 1024 + pos] +
              part[(size_t)(1 * 256 + co) * 1024 + pos] +
              part[(size_t)(2 * 256 + co) * 1024 + pos] +
              part[(size_t)(3 * 256 + co) * 1024 + pos];
    h4t[(size_t)pos * 256 + co] = fmaxf(v + bb, 0.f);
  }
}

// ---------------- head: reg(4)+cls(21) stride-1 conv + softmax/max/argmax ----
__global__ __launch_bounds__(256) void k_head(const float* __restrict__ h4t,
                                              const float* __restrict__ wh,
                                              const float* __restrict__ regb,
                                              const float* __restrict__ clsb,
                                              float* __restrict__ locs,
                                              float* __restrict__ confs,
                                              float* __restrict__ scores,
                                              float* __restrict__ labelsF) {
  const int pos = blockIdx.x;
  const int py = pos >> 5, px = pos & 31;
  const int t = threadIdx.x;
  float part[25] = {};
#pragma unroll
  for (int kh = 0; kh < 3; ++kh) {
    int iy = py + kh - 1;
    if (iy < 0 || iy > 31) continue;  // block-uniform
#pragma unroll
    for (int kw = 0; kw < 3; ++kw) {
      int ix = px + kw - 1;
      if (ix < 0 || ix > 31) continue;
      int tap = kh * 3 + kw;
      float v = h4t[(size_t)(iy * 32 + ix) * 256 + t];
      const float* wp = wh + (size_t)tap * 25 * 256 + t;
#pragma unroll
      for (int o = 0; o < 25; ++o)
        part[o] = fmaf(v, wp[(size_t)o * 256], part[o]);
    }
  }
#pragma unroll
  for (int o = 0; o < 25; ++o) {
#pragma unroll
    for (int d = 1; d < 64; d <<= 1) part[o] += __shfl_xor(part[o], d);
  }
  __shared__ float red[4][25];
  __shared__ float yv[25];
  const int wv = t >> 6, ln = t & 63;
  if (ln == 0) {
#pragma unroll
    for (int o = 0; o < 25; ++o) red[wv][o] = part[o];
  }
  __syncthreads();
  if (t < 25) {
    float y = red[0][t] + red[1][t] + red[2][t] + red[3][t];
    y += (t < 4) ? regb[t] : clsb[t - 4];
    if (t < 4) locs[(size_t)pos * 4 + t] = y;
    else       confs[(size_t)pos * 21 + (t - 4)] = y;
    yv[t] = y;
  }
  __syncthreads();
  if (t == 0) {
    float m = yv[4];
    int lab = 0;
    for (int j = 1; j < 21; ++j)
      if (yv[4 + j] > m) { m = yv[4 + j]; lab = j; }  // first-max semantics
    float s = 0.f;
    for (int j = 0; j < 21; ++j) s += expf(yv[4 + j] - m);
    scores[pos] = 1.f / s;   // max softmax prob
    labelsF[pos] = (float)lab;
  }
}

// ---------------- stable descending bitonic sort of 1024 scores --------------
__global__ __launch_bounds__(512) void k_sort(const float* __restrict__ scores,
                                              const float* __restrict__ locs,
                                              int* __restrict__ order,
                                              float* __restrict__ ssc,
                                              float* __restrict__ bsrt,
                                              unsigned long long* __restrict__ vbits) {
  __shared__ float sk[1024];
  __shared__ int   si[1024];
  const int t = threadIdx.x;
  sk[t] = scores[t];           si[t] = t;
  sk[t + 512] = scores[t + 512]; si[t + 512] = t + 512;
  for (int k = 2; k <= 1024; k <<= 1) {
    for (int j = k >> 1; j > 0; j >>= 1) {
      __syncthreads();
      int i1 = ((t / j) * (2 * j)) + (t % j);
      int i2 = i1 + j;
      bool up = (i1 & k) == 0;
      float sa = sk[i1], sb = sk[i2];
      int ia = si[i1], ib = si[i2];
      bool b_before_a = (sb > sa) || (sb == sa && ib < ia);
      bool a_before_b = (sa > sb) || (sa == sb && ia < ib);
      bool sw = up ? b_before_a : a_before_b;
      if (sw) { sk[i1] = sb; sk[i2] = sa; si[i1] = ib; si[i2] = ia; }
    }
  }
  __syncthreads();
  for (int i = t; i < 1024; i += 512) {
    int oi = si[i];
    order[i] = oi;
    ssc[i] = sk[i];
    ((float4*)bsrt)[i] = ((const float4*)locs)[oi];
  }
  if (t < 16) {  // validity bits (score > SCORE_THR), sorted order
    unsigned long long w = 0;
    for (int b2 = 0; b2 < 64; ++b2)
      if (sk[t * 64 + b2] > 0.04f) w |= (1ull << b2);
    vbits[t] = w;
  }
}

// ---------------- pairwise IoU suppression bitmask (1024x1024 bits) ----------
__global__ __launch_bounds__(256) void k_mask(const float* __restrict__ bsrt,
                                              unsigned long long* __restrict__ mask) {
  __shared__ float4 sb[1024];
  const int t = threadIdx.x;
  for (int idx = t; idx < 1024; idx += 256)
    sb[idx] = ((const float4*)bsrt)[idx];
  __syncthreads();
  const int i = blockIdx.x * 16 + (t & 15);
  const int w = t >> 4;
  float4 bi = sb[i];
  float ai = (bi.z - bi.x) * (bi.w - bi.y);
  unsigned long long bits = 0;
  for (int jj = 0; jj < 64; ++jj) {
    float4 bj = sb[w * 64 + jj];
    float aj = (bj.z - bj.x) * (bj.w - bj.y);
    float ltx = fmaxf(bi.x, bj.x), lty = fmaxf(bi.y, bj.y);
    float rbx = fminf(bi.z, bj.z), rby = fminf(bi.w, bj.w);
    float inter = fmaxf(rbx - ltx, 0.f) * fmaxf(rby - lty, 0.f);
    float uni = ai + aj - inter;
    float iou = inter / (uni + 1e-9f);
    if (iou > 0.5f) bits |= (1ull << jj);
  }
  mask[(size_t)i * 16 + w] = bits;
}

// ---------------- sequential greedy NMS scan (wave 0, LDS-staged halves) -----
__global__ __launch_bounds__(256) void k_scan(const unsigned long long* __restrict__ mask,
                                              const unsigned long long* __restrict__ vbits,
                                              unsigned long long* __restrict__ keepb) {
  __shared__ unsigned long long m_lds[512 * 16];  // exactly 64 KB
  const int t = threadIdx.x;
  unsigned long long keepm = 0, vw = 0;
  if (t < 16) vw = vbits[t];
  for (int ph = 0; ph < 2; ++ph) {
    __syncthreads();
    for (int idx = t; idx < 8192; idx += 256) m_lds[idx] = mask[ph * 8192 + idx];
    __syncthreads();
    if (t < 64) {
      for (int ii = 0; ii < 512; ++ii) {
        int i = ph * 512 + ii;
        unsigned long long row = (t < 16) ? m_lds[ii * 16 + t] : 0ull;
        bool hit = (row & keepm) != 0ull;
        bool sup = __any(hit);
        int wsel = i >> 6, bsel = i & 63;
        unsigned long long vword = __shfl(vw, wsel);
        bool vv = (vword >> bsel) & 1ull;
        bool kp = vv && !sup;
        if (kp && t == wsel) keepm |= (1ull << bsel);
      }
    }
  }
  __syncthreads();
  if (t < 16) keepb[t] = keepm;
}

// ---------------- final gather into d_out ------------------------------------
// layout: boxes[1024*4] | labels[1024] | scores[1024] | confs[1024*21]
__global__ __launch_bounds__(256) void k_gather(const unsigned long long* __restrict__ keepb,
                                                const int* __restrict__ order,
                                                const float* __restrict__ ssc,
                                                const float* __restrict__ locs,
                                                const float* __restrict__ confs,
                                                const float* __restrict__ labelsF,
                                                float* __restrict__ out) {
  int i = blockIdx.x * 256 + threadIdx.x;  // 0..1023
  bool k = (keepb[i >> 6] >> (i & 63)) & 1ull;
  int oi = order[i];
  float4 bx = k ? ((const float4*)locs)[oi] : make_float4(-1.f, -1.f, -1.f, -1.f);
  ((float4*)out)[i] = bx;
  out[4096 + i] = k ? labelsF[oi] : 0.f;
  out[5120 + i] = k ? ssc[i] : -1.f;
  float* oc = out + 6144 + (size_t)i * 21;
  const float* cc = confs + (size_t)oi * 21;
#pragma unroll
  for (int c = 0; c < 21; ++c) oc[c] = k ? cc[c] : -1.f;
}

// ============================================================================
extern "C" void kernel_launch(void* const* d_in, const int* in_sizes, int n_in,
                              void* d_out, int out_size, void* d_ws, size_t ws_size,
                              hipStream_t stream) {
  const float* x    = (const float*)d_in[0] + (size_t)7 * 3 * 512 * 512;  // image 7
  const float* w1   = (const float*)d_in[1];
  const float* b1   = (const float*)d_in[2];
  const float* w2   = (const float*)d_in[3];
  const float* b2   = (const float*)d_in[4];
  const float* w3   = (const float*)d_in[5];
  const float* b3   = (const float*)d_in[6];
  const float* w4   = (const float*)d_in[7];
  const float* b4   = (const float*)d_in[8];
  const float* regw = (const float*)d_in[9];
  const float* regb = (const float*)d_in[10];
  const float* clsw = (const float*)d_in[11];
  const float* clsb = (const float*)d_in[12];
  float* out = (float*)d_out;
  char* ws = (char*)d_ws;

  // region A (0..16.8MB): h1, then part4 + h4t
  float* h1    = (float*)(ws + 0);          // 16.8MB  (dead after conv2)
  float* part4 = (float*)(ws + 0);          // 4MB     (dead after combine)
  float* h4t   = (float*)(ws + 9437184);    // 1MB
  float* h2    = (float*)(ws + 16777216);   // 8.4MB   (dead after conv3)
  float* h3    = (float*)(ws + 25165824);   // 4.2MB
  float* wr2   = (float*)(ws + 29360128);
  float* wr3   = (float*)(ws + 29655040);
  float* wr4   = (float*)(ws + 30834688);
  float* wh    = (float*)(ws + 33193984);
  float* locs  = (float*)(ws + 33424384);
  float* confs = (float*)(ws + 33440768);
  float* scores  = (float*)(ws + 33526784);
  float* labelsF = (float*)(ws + 33530880);
  int*   order   = (int*)  (ws + 33534976);
  float* ssc     = (float*)(ws + 33539072);
  float* bsrt    = (float*)(ws + 33543168);
  unsigned long long* mask  = (unsigned long long*)(ws + 33559552);
  unsigned long long* vbits = (unsigned long long*)(ws + 33690624);
  unsigned long long* keepb = (unsigned long long*)(ws + 33690752);

  k_repack_w<<<288, 256, 0, stream>>>(w2, wr2, 64, 128, 73728);
  k_repack_w<<<1152, 256, 0, stream>>>(w3, wr3, 128, 256, 294912);
  k_repack_w<<<2304, 256, 0, stream>>>(w4, wr4, 256, 256, 589824);
  k_repack_head<<<225, 256, 0, stream>>>(regw, clsw, wh);

  k_conv1<<<dim3(16, 16, 2), dim3(16, 16), 0, stream>>>(x, w1, b1, h1);

  // conv2: 64->128, 256->128. 256 sp-tiles x 4 co-blocks = 1024 blocks, NST=2
  conv_s2<64, 128, 256, 256, 4, 16, 8, 32, 1, 19>
      <<<dim3(256, 4, 1), 256, 0, stream>>>(h1, wr2, b2, h2);
  // conv3: 128->256, 128->64. KSPLIT=1 (R0 numerics). 512 blocks, NST=4
  conv_s2<128, 256, 128, 128, 8, 8, 8, 32, 1, 9>
      <<<dim3(64, 8, 1), 256, 0, stream>>>(h2, wr3, b3, h3);
  // conv4: 256->256, 64->32. KSPLIT=4, 64-ci chunks (R0 numerics). NST=2
  conv_s2<256, 256, 64, 64, 8, 8, 8, 32, 4, 9>
      <<<dim3(16, 8, 4), 256, 0, stream>>>(h3, wr4, (const float*)nullptr, part4);
  k_combine<<<256, 256, 0, stream>>>(part4, b4, h4t);

  k_head<<<1024, 256, 0, stream>>>(h4t, wh, regb, clsb, locs, confs, scores, labelsF);

  k_sort<<<1, 512, 0, stream>>>(scores, locs, order, ssc, bsrt, vbits);
  k_mask<<<64, 256, 0, stream>>>(bsrt, mask);
  k_scan<<<1, 256, 0, stream>>>(mask, vbits, keepb);
  k_gather<<<4, 256, 0, stream>>>(keepb, order, ssc, locs, confs, labelsF, out);
}

// Round 5
// 496.358 us; speedup vs baseline: 1.7361x; 1.1456x over previous
//
#include <hip/hip_runtime.h>
#include <cstdint>
#include <cstddef>

// ============================================================================
// SSD forward (image 7 only) + NMS, all fp32.
// R4: occupancy push. COPT=4/CIT=16 (LDS ~20KB, grids 1024-2048 blocks ->
// 4-7 blocks/CU resident vs 2-3), float2-paired staging into de-interleaved
// even/odd planes, conv1 co-split x4, fused repacks, fused scan+gather.
// Per-output accumulation order (ci,kh,kw) + conv4 KSPLIT=4 w/ R0 combine
// unchanged — exact R0 numerics (passed 3x).
// ============================================================================

// ---------------- fused weight repack ----------------------------------------
// wr[(ci*9+tap)*COUT+co] from w[co][ci][3][3]; head: wh[(tap*25+o)*256+ci]
__global__ __launch_bounds__(256) void k_repack_all(
    const float* __restrict__ w2, const float* __restrict__ w3,
    const float* __restrict__ w4, const float* __restrict__ regw,
    const float* __restrict__ clsw, float* __restrict__ wr2,
    float* __restrict__ wr3, float* __restrict__ wr4, float* __restrict__ wh) {
  int idx = blockIdx.x * 256 + threadIdx.x;
  if (idx < 73728) {  // conv2: CIN=64 COUT=128
    int co = idx % 128, r = idx / 128, ci = r / 9, tap = r % 9;
    wr2[idx] = w2[(co * 64 + ci) * 9 + tap];
  } else if (idx < 73728 + 294912) {  // conv3: CIN=128 COUT=256
    int i = idx - 73728;
    int co = i % 256, r = i / 256, ci = r / 9, tap = r % 9;
    wr3[i] = w3[(co * 128 + ci) * 9 + tap];
  } else if (idx < 73728 + 294912 + 589824) {  // conv4: CIN=256 COUT=256
    int i = idx - (73728 + 294912);
    int co = i % 256, r = i / 256, ci = r / 9, tap = r % 9;
    wr4[i] = w4[(co * 256 + ci) * 9 + tap];
  } else if (idx < 73728 + 294912 + 589824 + 57600) {  // head
    int i = idx - (73728 + 294912 + 589824);
    int ci = i & 255, r = i >> 8, tap = r / 25, o = r % 25;
    wh[i] = (o < 4) ? regw[(o * 256 + ci) * 9 + tap]
                    : clsw[((o - 4) * 256 + ci) * 9 + tap];
  }
}

// ---------------- conv1: 3->64, 512->256, stride 2, co-split by blockIdx.z ---
__global__ __launch_bounds__(256) void k_conv1(const float* __restrict__ x,
                                               const float* __restrict__ w,
                                               const float* __restrict__ b,
                                               float* __restrict__ out) {
  __shared__ float in_t[3][33][33];
  const int tx = threadIdx.x, ty = threadIdx.y;
  const int tid = ty * 16 + tx;
  const int ox0 = blockIdx.x * 16, oy0 = blockIdx.y * 16;
  const int co0 = blockIdx.z * 16;
  for (int idx = tid; idx < 3 * 33 * 33; idx += 256) {
    int ci = idx / 1089, rem = idx % 1089;
    int r = rem / 33, c = rem % 33;
    int iy = oy0 * 2 + r, ix = ox0 * 2 + c;
    float v = 0.f;
    if (iy < 512 && ix < 512) v = x[(size_t)ci * 262144 + iy * 512 + ix];
    in_t[ci][r][c] = v;
  }
  __syncthreads();
  float rin[27];
#pragma unroll
  for (int ci = 0; ci < 3; ++ci)
#pragma unroll
    for (int kh = 0; kh < 3; ++kh)
#pragma unroll
      for (int kw = 0; kw < 3; ++kw)
        rin[ci * 9 + kh * 3 + kw] = in_t[ci][2 * ty + kh][2 * tx + kw];
  const int oy = oy0 + ty, ox = ox0 + tx;
  for (int co = co0; co < co0 + 16; ++co) {  // co uniform -> weights via s_load
    float a = 0.f;
#pragma unroll
    for (int k = 0; k < 27; ++k) a = fmaf(w[co * 27 + k], rin[k], a);
    out[(size_t)co * 65536 + oy * 256 + ox] = fmaxf(a + b[co], 0.f);
  }
}

// ---------------- generic stride-2 3x3 conv, SAME(pad lo 0 hi 1) -------------
// 256 thr = 4 co-groups (wave-uniform cout via readfirstlane) x 64 lanes.
// Lane lp -> output position (py=lp/SW, px=lp%SW); SH*SW == 64.
// LDS: EV plane (even input cols) + OD plane (odd input cols), row stride
// PADW -> stride-2 conv reads become stride-1. Staging loads float2 pairs
// (even col -> EV, odd col -> OD). 2 barriers/stage, CIT=16 (LDS ~20KB).
// Per-output accumulation order: (ci,kh,kw) lexicographic — matches R0.
template <int CIN, int COUT, int HIN, int WIN, int SH, int SW, int COPT,
          int CIT, int KSPLIT, int PADW>
__global__ __launch_bounds__(256) void conv_s2(const float* __restrict__ in,
                                               const float* __restrict__ wr,
                                               const float* __restrict__ bias,
                                               float* __restrict__ out) {
  constexpr int HOUT = HIN / 2, WOUT = WIN / 2;
  constexpr int IH = SH * 2 + 1, IW = SW * 2 + 1, IW2 = (IW + 1) / 2;
  constexpr int COT = 4 * COPT;
  constexpr int ODOFF = CIT * IH * PADW;
  constexpr int TOT2 = CIT * IH * IW2;
  static_assert(SH * SW == 64, "one position per lane");
  __shared__ float lds[2 * ODOFF];

  const int tid = threadIdx.x;
  const int gu  = __builtin_amdgcn_readfirstlane(tid >> 6);
  const int lp  = tid & 63;
  const int py  = lp / SW, px = lp % SW;

  constexpr int ntx = WOUT / SW;
  const int bx = blockIdx.x % ntx, by = blockIdx.x / ntx;
  const int ox0 = bx * SW, oy0 = by * SH;
  const int co_blk = blockIdx.y * COT;
  const int cobase = co_blk + gu * COPT;
  const int ci_begin = (KSPLIT > 1) ? blockIdx.z * (CIN / KSPLIT) : 0;
  constexpr int NST = (CIN / KSPLIT) / CIT;

  float acc[COPT] = {};

  for (int st = 0; st < NST; ++st) {
    const int cib = ci_begin + st * CIT;
    if (st) __syncthreads();   // protect previous stage's reads
    // ---- staging: global float2 pairs -> de-interleaved LDS planes ----
    for (int idx = tid; idx < TOT2; idx += 256) {
      int ci = idx / (IH * IW2), rem = idx % (IH * IW2);
      int r = rem / IW2, c2 = rem % IW2;
      int c = 2 * c2;
      int iy = oy0 * 2 + r, ix = ox0 * 2 + c;
      float v0 = 0.f, v1 = 0.f;
      const float* src = in + (size_t)(cib + ci) * HIN * WIN;
      if (iy < HIN) {
        if ((c + 1 < IW) && (ix + 1 < WIN)) {
          float2 t = *(const float2*)(src + (size_t)iy * WIN + ix);
          v0 = t.x; v1 = t.y;
        } else if (ix < WIN) {
          v0 = src[(size_t)iy * WIN + ix];
        }
      }
      int slot = (ci * IH + r) * PADW + c2;
      lds[slot] = v0;           // even col plane
      lds[ODOFF + slot] = v1;   // odd col plane
    }
    __syncthreads();
    // ---- compute ----
#pragma unroll 2
    for (int ci = 0; ci < CIT; ++ci) {
#pragma unroll
      for (int kh = 0; kh < 3; ++kh) {
        const int row = (ci * IH + 2 * py + kh) * PADW;
        float e0 = lds[row + px];          // kw=0 : col 2px
        float o0 = lds[ODOFF + row + px];  // kw=1 : col 2px+1
        float e1 = lds[row + px + 1];      // kw=2 : col 2px+2
        const float* wp =
            wr + ((size_t)(cib + ci) * 9 + kh * 3) * COUT + cobase;
#pragma unroll
        for (int c = 0; c < COPT; ++c) acc[c] = fmaf(e0, wp[c], acc[c]);
#pragma unroll
        for (int c = 0; c < COPT; ++c) acc[c] = fmaf(o0, wp[COUT + c], acc[c]);
#pragma unroll
        for (int c = 0; c < COPT; ++c) acc[c] = fmaf(e1, wp[2 * COUT + c], acc[c]);
      }
    }
  }

  const int oy = oy0 + py, ox = ox0 + px;
#pragma unroll
  for (int c = 0; c < COPT; ++c) {
    int co = cobase + c;
    if constexpr (KSPLIT > 1) {
      out[((size_t)blockIdx.z * COUT + co) * (HOUT * WOUT) + oy * WOUT + ox] =
          acc[c];
    } else {
      out[(size_t)co * (HOUT * WOUT) + oy * WOUT + ox] =
          fmaxf(acc[c] + bias[co], 0.f);
    }
  }
}

// ---------------- combine conv4 K-split partials + bias + relu, write NHWC ---
// EXACT R0 semantics: v = ((p0+p1)+p2)+p3; out = max(v+b, 0)
__global__ __launch_bounds__(256) void k_combine(const float* __restrict__ part,
                                                 const float* __restrict__ b,
                                                 float* __restrict__ h4t) {
  int co = blockIdx.x;  // 0..255
  float bb = b[co];
  for (int k2 = 0; k2 < 4; ++k2) {
    int pos = threadIdx.x + k2 * 256;
    float v = part[(size_t)(0 * 256 + co) * 1024 + pos] +
              part[(size_t)(1 * 256 + co) * 1024 + pos] +
              part[(size_t)(2 * 256 + co) * 1024 + pos] +
              part[(size_t)(3 * 256 + co) * 1024 + pos];
    h4t[(size_t)pos * 256 + co] = fmaxf(v + bb, 0.f);
  }
}

// ---------------- head: reg(4)+cls(21) stride-1 conv + softmax/max/argmax ----
__global__ __launch_bounds__(256) void k_head(const float* __restrict__ h4t,
                                              const float* __restrict__ wh,
                                              const float* __restrict__ regb,
                                              const float* __restrict__ clsb,
                                              float* __restrict__ locs,
                                              float* __restrict__ confs,
                                              float* __restrict__ scores,
                                              float* __restrict__ labelsF) {
  const int pos = blockIdx.x;
  const int py = pos >> 5, px = pos & 31;
  const int t = threadIdx.x;
  float part[25] = {};
#pragma unroll
  for (int kh = 0; kh < 3; ++kh) {
    int iy = py + kh - 1;
    if (iy < 0 || iy > 31) continue;  // block-uniform
#pragma unroll
    for (int kw = 0; kw < 3; ++kw) {
      int ix = px + kw - 1;
      if (ix < 0 || ix > 31) continue;
      int tap = kh * 3 + kw;
      float v = h4t[(size_t)(iy * 32 + ix) * 256 + t];
      const float* wp = wh + (size_t)tap * 25 * 256 + t;
#pragma unroll
      for (int o = 0; o < 25; ++o)
        part[o] = fmaf(v, wp[(size_t)o * 256], part[o]);
    }
  }
#pragma unroll
  for (int o = 0; o < 25; ++o) {
#pragma unroll
    for (int d = 1; d < 64; d <<= 1) part[o] += __shfl_xor(part[o], d);
  }
  __shared__ float red[4][25];
  __shared__ float yv[25];
  const int wv = t >> 6, ln = t & 63;
  if (ln == 0) {
#pragma unroll
    for (int o = 0; o < 25; ++o) red[wv][o] = part[o];
  }
  __syncthreads();
  if (t < 25) {
    float y = red[0][t] + red[1][t] + red[2][t] + red[3][t];
    y += (t < 4) ? regb[t] : clsb[t - 4];
    if (t < 4) locs[(size_t)pos * 4 + t] = y;
    else       confs[(size_t)pos * 21 + (t - 4)] = y;
    yv[t] = y;
  }
  __syncthreads();
  if (t == 0) {
    float m = yv[4];
    int lab = 0;
    for (int j = 1; j < 21; ++j)
      if (yv[4 + j] > m) { m = yv[4 + j]; lab = j; }  // first-max semantics
    float s = 0.f;
    for (int j = 0; j < 21; ++j) s += expf(yv[4 + j] - m);
    scores[pos] = 1.f / s;   // max softmax prob
    labelsF[pos] = (float)lab;
  }
}

// ---------------- stable descending bitonic sort of 1024 scores --------------
__global__ __launch_bounds__(512) void k_sort(const float* __restrict__ scores,
                                              const float* __restrict__ locs,
                                              int* __restrict__ order,
                                              float* __restrict__ ssc,
                                              float* __restrict__ bsrt,
                                              unsigned long long* __restrict__ vbits) {
  __shared__ float sk[1024];
  __shared__ int   si[1024];
  const int t = threadIdx.x;
  sk[t] = scores[t];           si[t] = t;
  sk[t + 512] = scores[t + 512]; si[t + 512] = t + 512;
  for (int k = 2; k <= 1024; k <<= 1) {
    for (int j = k >> 1; j > 0; j >>= 1) {
      __syncthreads();
      int i1 = ((t / j) * (2 * j)) + (t % j);
      int i2 = i1 + j;
      bool up = (i1 & k) == 0;
      float sa = sk[i1], sb = sk[i2];
      int ia = si[i1], ib = si[i2];
      bool b_before_a = (sb > sa) || (sb == sa && ib < ia);
      bool a_before_b = (sa > sb) || (sa == sb && ia < ib);
      bool sw = up ? b_before_a : a_before_b;
      if (sw) { sk[i1] = sb; sk[i2] = sa; si[i1] = ib; si[i2] = ia; }
    }
  }
  __syncthreads();
  for (int i = t; i < 1024; i += 512) {
    int oi = si[i];
    order[i] = oi;
    ssc[i] = sk[i];
    ((float4*)bsrt)[i] = ((const float4*)locs)[oi];
  }
  if (t < 16) {  // validity bits (score > SCORE_THR), sorted order
    unsigned long long w = 0;
    for (int b2 = 0; b2 < 64; ++b2)
      if (sk[t * 64 + b2] > 0.04f) w |= (1ull << b2);
    vbits[t] = w;
  }
}

// ---------------- pairwise IoU suppression bitmask (1024x1024 bits) ----------
__global__ __launch_bounds__(256) void k_mask(const float* __restrict__ bsrt,
                                              unsigned long long* __restrict__ mask) {
  __shared__ float4 sb[1024];
  const int t = threadIdx.x;
  for (int idx = t; idx < 1024; idx += 256)
    sb[idx] = ((const float4*)bsrt)[idx];
  __syncthreads();
  const int i = blockIdx.x * 16 + (t & 15);
  const int w = t >> 4;
  float4 bi = sb[i];
  float ai = (bi.z - bi.x) * (bi.w - bi.y);
  unsigned long long bits = 0;
  for (int jj = 0; jj < 64; ++jj) {
    float4 bj = sb[w * 64 + jj];
    float aj = (bj.z - bj.x) * (bj.w - bj.y);
    float ltx = fmaxf(bi.x, bj.x), lty = fmaxf(bi.y, bj.y);
    float rbx = fminf(bi.z, bj.z), rby = fminf(bi.w, bj.w);
    float inter = fmaxf(rbx - ltx, 0.f) * fmaxf(rby - lty, 0.f);
    float uni = ai + aj - inter;
    float iou = inter / (uni + 1e-9f);
    if (iou > 0.5f) bits |= (1ull << jj);
  }
  mask[(size_t)i * 16 + w] = bits;
}

// ---------------- sequential greedy NMS scan + fused gather ------------------
// layout: boxes[1024*4] | labels[1024] | scores[1024] | confs[1024*21]
__global__ __launch_bounds__(256) void k_scan_gather(
    const unsigned long long* __restrict__ mask,
    const unsigned long long* __restrict__ vbits,
    const int* __restrict__ order, const float* __restrict__ ssc,
    const float* __restrict__ locs, const float* __restrict__ confs,
    const float* __restrict__ labelsF, float* __restrict__ out) {
  __shared__ unsigned long long m_lds[512 * 16];  // exactly 64 KB
  __shared__ unsigned long long keep_lds[16];
  const int t = threadIdx.x;
  unsigned long long keepm = 0, vw = 0;
  if (t < 16) vw = vbits[t];
  for (int ph = 0; ph < 2; ++ph) {
    __syncthreads();
    for (int idx = t; idx < 8192; idx += 256) m_lds[idx] = mask[ph * 8192 + idx];
    __syncthreads();
    if (t < 64) {
      for (int ii = 0; ii < 512; ++ii) {
        int i = ph * 512 + ii;
        unsigned long long row = (t < 16) ? m_lds[ii * 16 + t] : 0ull;
        bool hit = (row & keepm) != 0ull;
        bool sup = __any(hit);
        int wsel = i >> 6, bsel = i & 63;
        unsigned long long vword = __shfl(vw, wsel);
        bool vv = (vword >> bsel) & 1ull;
        bool kp = vv && !sup;
        if (kp && t == wsel) keepm |= (1ull << bsel);
      }
    }
  }
  __syncthreads();
  if (t < 16) keep_lds[t] = keepm;
  __syncthreads();
  for (int i = t; i < 1024; i += 256) {
    bool k = (keep_lds[i >> 6] >> (i & 63)) & 1ull;
    int oi = order[i];
    float4 bx = k ? ((const float4*)locs)[oi]
                  : make_float4(-1.f, -1.f, -1.f, -1.f);
    ((float4*)out)[i] = bx;
    out[4096 + i] = k ? labelsF[oi] : 0.f;
    out[5120 + i] = k ? ssc[i] : -1.f;
    float* oc = out + 6144 + (size_t)i * 21;
    const float* cc = confs + (size_t)oi * 21;
#pragma unroll
    for (int c = 0; c < 21; ++c) oc[c] = k ? cc[c] : -1.f;
  }
}

// ============================================================================
extern "C" void kernel_launch(void* const* d_in, const int* in_sizes, int n_in,
                              void* d_out, int out_size, void* d_ws, size_t ws_size,
                              hipStream_t stream) {
  const float* x    = (const float*)d_in[0] + (size_t)7 * 3 * 512 * 512;  // image 7
  const float* w1   = (const float*)d_in[1];
  const float* b1   = (const float*)d_in[2];
  const float* w2   = (const float*)d_in[3];
  const float* b2   = (const float*)d_in[4];
  const float* w3   = (const float*)d_in[5];
  const float* b3   = (const float*)d_in[6];
  const float* w4   = (const float*)d_in[7];
  const float* b4   = (const float*)d_in[8];
  const float* regw = (const float*)d_in[9];
  const float* regb = (const float*)d_in[10];
  const float* clsw = (const float*)d_in[11];
  const float* clsb = (const float*)d_in[12];
  float* out = (float*)d_out;
  char* ws = (char*)d_ws;

  // region A (0..16.8MB): h1, then part4 + h4t
  float* h1    = (float*)(ws + 0);          // 16.8MB  (dead after conv2)
  float* part4 = (float*)(ws + 0);          // 4MB     (dead after combine)
  float* h4t   = (float*)(ws + 9437184);    // 1MB
  float* h2    = (float*)(ws + 16777216);   // 8.4MB   (dead after conv3)
  float* h3    = (float*)(ws + 25165824);   // 4.2MB
  float* wr2   = (float*)(ws + 29360128);
  float* wr3   = (float*)(ws + 29655040);
  float* wr4   = (float*)(ws + 30834688);
  float* wh    = (float*)(ws + 33193984);
  float* locs  = (float*)(ws + 33424384);
  float* confs = (float*)(ws + 33440768);
  float* scores  = (float*)(ws + 33526784);
  float* labelsF = (float*)(ws + 33530880);
  int*   order   = (int*)  (ws + 33534976);
  float* ssc     = (float*)(ws + 33539072);
  float* bsrt    = (float*)(ws + 33543168);
  unsigned long long* mask  = (unsigned long long*)(ws + 33559552);
  unsigned long long* vbits = (unsigned long long*)(ws + 33690624);

  k_repack_all<<<3969, 256, 0, stream>>>(w2, w3, w4, regw, clsw,
                                         wr2, wr3, wr4, wh);

  k_conv1<<<dim3(16, 16, 4), dim3(16, 16), 0, stream>>>(x, w1, b1, h1);

  // conv2: 64->128, 256->128. 256 sp x 8 co = 2048 blocks, NST=4, LDS ~21KB
  conv_s2<64, 128, 256, 256, 4, 16, 4, 16, 1, 19>
      <<<dim3(256, 8, 1), 256, 0, stream>>>(h1, wr2, b2, h2);
  // conv3: 128->256, 128->64. KSPLIT=1 (R0 numerics). 64 sp x 16 co = 1024
  conv_s2<128, 256, 128, 128, 8, 8, 4, 16, 1, 9>
      <<<dim3(64, 16, 1), 256, 0, stream>>>(h2, wr3, b3, h3);
  // conv4: 256->256, 64->32. KSPLIT=4, 64-ci chunks (R0 numerics). 1024 blocks
  conv_s2<256, 256, 64, 64, 8, 8, 4, 16, 4, 9>
      <<<dim3(16, 16, 4), 256, 0, stream>>>(h3, wr4, (const float*)nullptr, part4);
  k_combine<<<256, 256, 0, stream>>>(part4, b4, h4t);

  k_head<<<1024, 256, 0, stream>>>(h4t, wh, regb, clsb, locs, confs, scores, labelsF);

  k_sort<<<1, 512, 0, stream>>>(scores, locs, order, ssc, bsrt, vbits);
  k_mask<<<64, 256, 0, stream>>>(bsrt, mask);
  k_scan_gather<<<1, 256, 0, stream>>>(mask, vbits, order, ssc, locs, confs,
                                       labelsF, out);
}

// Round 6
// 475.029 us; speedup vs baseline: 1.8141x; 1.0449x over previous
//
#include <hip/hip_runtime.h>
#include <cstdint>
#include <cstddef>

// ============================================================================
// SSD forward (image 7 only) + NMS, all fp32.
// R5: NMS scan rewritten as chunked ballot-scan (64-box chunks): intra-chunk
// serial scan is register/SALU only (row held in lane i's VGPRs, keep word
// built via __ballot) — no LDS/shfl in the dependency chain; suppression
// propagation is batch-parallel mask-row ORs. Bit-identical keep decisions.
// Convs/head/sort unchanged from R4 (passed, absmax 9.8e-4).
// ============================================================================

// ---------------- fused weight repack ----------------------------------------
// wr[(ci*9+tap)*COUT+co] from w[co][ci][3][3]; head: wh[(tap*25+o)*256+ci]
__global__ __launch_bounds__(256) void k_repack_all(
    const float* __restrict__ w2, const float* __restrict__ w3,
    const float* __restrict__ w4, const float* __restrict__ regw,
    const float* __restrict__ clsw, float* __restrict__ wr2,
    float* __restrict__ wr3, float* __restrict__ wr4, float* __restrict__ wh) {
  int idx = blockIdx.x * 256 + threadIdx.x;
  if (idx < 73728) {  // conv2: CIN=64 COUT=128
    int co = idx % 128, r = idx / 128, ci = r / 9, tap = r % 9;
    wr2[idx] = w2[(co * 64 + ci) * 9 + tap];
  } else if (idx < 73728 + 294912) {  // conv3: CIN=128 COUT=256
    int i = idx - 73728;
    int co = i % 256, r = i / 256, ci = r / 9, tap = r % 9;
    wr3[i] = w3[(co * 128 + ci) * 9 + tap];
  } else if (idx < 73728 + 294912 + 589824) {  // conv4: CIN=256 COUT=256
    int i = idx - (73728 + 294912);
    int co = i % 256, r = i / 256, ci = r / 9, tap = r % 9;
    wr4[i] = w4[(co * 256 + ci) * 9 + tap];
  } else if (idx < 73728 + 294912 + 589824 + 57600) {  // head
    int i = idx - (73728 + 294912 + 589824);
    int ci = i & 255, r = i >> 8, tap = r / 25, o = r % 25;
    wh[i] = (o < 4) ? regw[(o * 256 + ci) * 9 + tap]
                    : clsw[((o - 4) * 256 + ci) * 9 + tap];
  }
}

// ---------------- conv1: 3->64, 512->256, stride 2, co-split by blockIdx.z ---
__global__ __launch_bounds__(256) void k_conv1(const float* __restrict__ x,
                                               const float* __restrict__ w,
                                               const float* __restrict__ b,
                                               float* __restrict__ out) {
  __shared__ float in_t[3][33][33];
  const int tx = threadIdx.x, ty = threadIdx.y;
  const int tid = ty * 16 + tx;
  const int ox0 = blockIdx.x * 16, oy0 = blockIdx.y * 16;
  const int co0 = blockIdx.z * 16;
  for (int idx = tid; idx < 3 * 33 * 33; idx += 256) {
    int ci = idx / 1089, rem = idx % 1089;
    int r = rem / 33, c = rem % 33;
    int iy = oy0 * 2 + r, ix = ox0 * 2 + c;
    float v = 0.f;
    if (iy < 512 && ix < 512) v = x[(size_t)ci * 262144 + iy * 512 + ix];
    in_t[ci][r][c] = v;
  }
  __syncthreads();
  float rin[27];
#pragma unroll
  for (int ci = 0; ci < 3; ++ci)
#pragma unroll
    for (int kh = 0; kh < 3; ++kh)
#pragma unroll
      for (int kw = 0; kw < 3; ++kw)
        rin[ci * 9 + kh * 3 + kw] = in_t[ci][2 * ty + kh][2 * tx + kw];
  const int oy = oy0 + ty, ox = ox0 + tx;
  for (int co = co0; co < co0 + 16; ++co) {  // co uniform -> weights via s_load
    float a = 0.f;
#pragma unroll
    for (int k = 0; k < 27; ++k) a = fmaf(w[co * 27 + k], rin[k], a);
    out[(size_t)co * 65536 + oy * 256 + ox] = fmaxf(a + b[co], 0.f);
  }
}

// ---------------- generic stride-2 3x3 conv, SAME(pad lo 0 hi 1) -------------
// 256 thr = 4 co-groups (wave-uniform cout via readfirstlane) x 64 lanes.
// Lane lp -> output position (py=lp/SW, px=lp%SW); SH*SW == 64.
// LDS: EV plane (even input cols) + OD plane (odd input cols), row stride
// PADW -> stride-2 conv reads become stride-1. Staging loads float2 pairs.
// Per-output accumulation order: (ci,kh,kw) lexicographic — matches R0.
template <int CIN, int COUT, int HIN, int WIN, int SH, int SW, int COPT,
          int CIT, int KSPLIT, int PADW>
__global__ __launch_bounds__(256) void conv_s2(const float* __restrict__ in,
                                               const float* __restrict__ wr,
                                               const float* __restrict__ bias,
                                               float* __restrict__ out) {
  constexpr int HOUT = HIN / 2, WOUT = WIN / 2;
  constexpr int IH = SH * 2 + 1, IW = SW * 2 + 1, IW2 = (IW + 1) / 2;
  constexpr int COT = 4 * COPT;
  constexpr int ODOFF = CIT * IH * PADW;
  constexpr int TOT2 = CIT * IH * IW2;
  static_assert(SH * SW == 64, "one position per lane");
  __shared__ float lds[2 * ODOFF];

  const int tid = threadIdx.x;
  const int gu  = __builtin_amdgcn_readfirstlane(tid >> 6);
  const int lp  = tid & 63;
  const int py  = lp / SW, px = lp % SW;

  constexpr int ntx = WOUT / SW;
  const int bx = blockIdx.x % ntx, by = blockIdx.x / ntx;
  const int ox0 = bx * SW, oy0 = by * SH;
  const int co_blk = blockIdx.y * COT;
  const int cobase = co_blk + gu * COPT;
  const int ci_begin = (KSPLIT > 1) ? blockIdx.z * (CIN / KSPLIT) : 0;
  constexpr int NST = (CIN / KSPLIT) / CIT;

  float acc[COPT] = {};

  for (int st = 0; st < NST; ++st) {
    const int cib = ci_begin + st * CIT;
    if (st) __syncthreads();   // protect previous stage's reads
    // ---- staging: global float2 pairs -> de-interleaved LDS planes ----
    for (int idx = tid; idx < TOT2; idx += 256) {
      int ci = idx / (IH * IW2), rem = idx % (IH * IW2);
      int r = rem / IW2, c2 = rem % IW2;
      int c = 2 * c2;
      int iy = oy0 * 2 + r, ix = ox0 * 2 + c;
      float v0 = 0.f, v1 = 0.f;
      const float* src = in + (size_t)(cib + ci) * HIN * WIN;
      if (iy < HIN) {
        if ((c + 1 < IW) && (ix + 1 < WIN)) {
          float2 t = *(const float2*)(src + (size_t)iy * WIN + ix);
          v0 = t.x; v1 = t.y;
        } else if (ix < WIN) {
          v0 = src[(size_t)iy * WIN + ix];
        }
      }
      int slot = (ci * IH + r) * PADW + c2;
      lds[slot] = v0;           // even col plane
      lds[ODOFF + slot] = v1;   // odd col plane
    }
    __syncthreads();
    // ---- compute ----
#pragma unroll 2
    for (int ci = 0; ci < CIT; ++ci) {
#pragma unroll
      for (int kh = 0; kh < 3; ++kh) {
        const int row = (ci * IH + 2 * py + kh) * PADW;
        float e0 = lds[row + px];          // kw=0 : col 2px
        float o0 = lds[ODOFF + row + px];  // kw=1 : col 2px+1
        float e1 = lds[row + px + 1];      // kw=2 : col 2px+2
        const float* wp =
            wr + ((size_t)(cib + ci) * 9 + kh * 3) * COUT + cobase;
#pragma unroll
        for (int c = 0; c < COPT; ++c) acc[c] = fmaf(e0, wp[c], acc[c]);
#pragma unroll
        for (int c = 0; c < COPT; ++c) acc[c] = fmaf(o0, wp[COUT + c], acc[c]);
#pragma unroll
        for (int c = 0; c < COPT; ++c) acc[c] = fmaf(e1, wp[2 * COUT + c], acc[c]);
      }
    }
  }

  const int oy = oy0 + py, ox = ox0 + px;
#pragma unroll
  for (int c = 0; c < COPT; ++c) {
    int co = cobase + c;
    if constexpr (KSPLIT > 1) {
      out[((size_t)blockIdx.z * COUT + co) * (HOUT * WOUT) + oy * WOUT + ox] =
          acc[c];
    } else {
      out[(size_t)co * (HOUT * WOUT) + oy * WOUT + ox] =
          fmaxf(acc[c] + bias[co], 0.f);
    }
  }
}

// ---------------- combine conv4 K-split partials + bias + relu, write NHWC ---
// EXACT R0 semantics: v = ((p0+p1)+p2)+p3; out = max(v+b, 0)
__global__ __launch_bounds__(256) void k_combine(const float* __restrict__ part,
                                                 const float* __restrict__ b,
                                                 float* __restrict__ h4t) {
  int co = blockIdx.x;  // 0..255
  float bb = b[co];
  for (int k2 = 0; k2 < 4; ++k2) {
    int pos = threadIdx.x + k2 * 256;
    float v = part[(size_t)(0 * 256 + co) * 1024 + pos] +
              part[(size_t)(1 * 256 + co) * 1024 + pos] +
              part[(size_t)(2 * 256 + co) * 1024 + pos] +
              part[(size_t)(3 * 256 + co) * 1024 + pos];
    h4t[(size_t)pos * 256 + co] = fmaxf(v + bb, 0.f);
  }
}

// ---------------- head: reg(4)+cls(21) stride-1 conv + softmax/max/argmax ----
__global__ __launch_bounds__(256) void k_head(const float* __restrict__ h4t,
                                              const float* __restrict__ wh,
                                              const float* __restrict__ regb,
                                              const float* __restrict__ clsb,
                                              float* __restrict__ locs,
                                              float* __restrict__ confs,
                                              float* __restrict__ scores,
                                              float* __restrict__ labelsF) {
  const int pos = blockIdx.x;
  const int py = pos >> 5, px = pos & 31;
  const int t = threadIdx.x;
  float part[25] = {};
#pragma unroll
  for (int kh = 0; kh < 3; ++kh) {
    int iy = py + kh - 1;
    if (iy < 0 || iy > 31) continue;  // block-uniform
#pragma unroll
    for (int kw = 0; kw < 3; ++kw) {
      int ix = px + kw - 1;
      if (ix < 0 || ix > 31) continue;
      int tap = kh * 3 + kw;
      float v = h4t[(size_t)(iy * 32 + ix) * 256 + t];
      const float* wp = wh + (size_t)tap * 25 * 256 + t;
#pragma unroll
      for (int o = 0; o < 25; ++o)
        part[o] = fmaf(v, wp[(size_t)o * 256], part[o]);
    }
  }
#pragma unroll
  for (int o = 0; o < 25; ++o) {
#pragma unroll
    for (int d = 1; d < 64; d <<= 1) part[o] += __shfl_xor(part[o], d);
  }
  __shared__ float red[4][25];
  __shared__ float yv[25];
  const int wv = t >> 6, ln = t & 63;
  if (ln == 0) {
#pragma unroll
    for (int o = 0; o < 25; ++o) red[wv][o] = part[o];
  }
  __syncthreads();
  if (t < 25) {
    float y = red[0][t] + red[1][t] + red[2][t] + red[3][t];
    y += (t < 4) ? regb[t] : clsb[t - 4];
    if (t < 4) locs[(size_t)pos * 4 + t] = y;
    else       confs[(size_t)pos * 21 + (t - 4)] = y;
    yv[t] = y;
  }
  __syncthreads();
  if (t == 0) {
    float m = yv[4];
    int lab = 0;
    for (int j = 1; j < 21; ++j)
      if (yv[4 + j] > m) { m = yv[4 + j]; lab = j; }  // first-max semantics
    float s = 0.f;
    for (int j = 0; j < 21; ++j) s += expf(yv[4 + j] - m);
    scores[pos] = 1.f / s;   // max softmax prob
    labelsF[pos] = (float)lab;
  }
}

// ---------------- stable descending bitonic sort of 1024 scores --------------
__global__ __launch_bounds__(512) void k_sort(const float* __restrict__ scores,
                                              const float* __restrict__ locs,
                                              int* __restrict__ order,
                                              float* __restrict__ ssc,
                                              float* __restrict__ bsrt,
                                              unsigned long long* __restrict__ vbits) {
  __shared__ float sk[1024];
  __shared__ int   si[1024];
  const int t = threadIdx.x;
  sk[t] = scores[t];           si[t] = t;
  sk[t + 512] = scores[t + 512]; si[t + 512] = t + 512;
  for (int k = 2; k <= 1024; k <<= 1) {
    for (int j = k >> 1; j > 0; j >>= 1) {
      __syncthreads();
      int i1 = ((t / j) * (2 * j)) + (t % j);
      int i2 = i1 + j;
      bool up = (i1 & k) == 0;
      float sa = sk[i1], sb = sk[i2];
      int ia = si[i1], ib = si[i2];
      bool b_before_a = (sb > sa) || (sb == sa && ib < ia);
      bool a_before_b = (sa > sb) || (sa == sb && ia < ib);
      bool sw = up ? b_before_a : a_before_b;
      if (sw) { sk[i1] = sb; sk[i2] = sa; si[i1] = ib; si[i2] = ia; }
    }
  }
  __syncthreads();
  for (int i = t; i < 1024; i += 512) {
    int oi = si[i];
    order[i] = oi;
    ssc[i] = sk[i];
    ((float4*)bsrt)[i] = ((const float4*)locs)[oi];
  }
  if (t < 16) {  // validity bits (score > SCORE_THR), sorted order
    unsigned long long w = 0;
    for (int b2 = 0; b2 < 64; ++b2)
      if (sk[t * 64 + b2] > 0.04f) w |= (1ull << b2);
    vbits[t] = w;
  }
}

// ---------------- pairwise IoU suppression bitmask (1024x1024 bits) ----------
__global__ __launch_bounds__(256) void k_mask(const float* __restrict__ bsrt,
                                              unsigned long long* __restrict__ mask) {
  __shared__ float4 sb[1024];
  const int t = threadIdx.x;
  for (int idx = t; idx < 1024; idx += 256)
    sb[idx] = ((const float4*)bsrt)[idx];
  __syncthreads();
  const int i = blockIdx.x * 16 + (t & 15);
  const int w = t >> 4;
  float4 bi = sb[i];
  float ai = (bi.z - bi.x) * (bi.w - bi.y);
  unsigned long long bits = 0;
  for (int jj = 0; jj < 64; ++jj) {
    float4 bj = sb[w * 64 + jj];
    float aj = (bj.z - bj.x) * (bj.w - bj.y);
    float ltx = fmaxf(bi.x, bj.x), lty = fmaxf(bi.y, bj.y);
    float rbx = fminf(bi.z, bj.z), rby = fminf(bi.w, bj.w);
    float inter = fmaxf(rbx - ltx, 0.f) * fmaxf(rby - lty, 0.f);
    float uni = ai + aj - inter;
    float iou = inter / (uni + 1e-9f);
    if (iou > 0.5f) bits |= (1ull << jj);
  }
  mask[(size_t)i * 16 + w] = bits;
}

// ---------------- chunked ballot-scan greedy NMS + fused gather --------------
// One wave (64 threads). 16 chunks of 64 boxes each (sorted order).
// Intra-chunk: lane i holds mask row word (chunk-internal cols) in a register;
// 64-step serial scan is pure VALU/SALU: K |= __ballot(valid && (row&K)==0)&bit.
// Apply: all 64 lanes OR the kept rows' words (16 indep loads/lane, select-
// masked), reduce across 4 lane-groups via shfl_xor. Bit-identical decisions.
// layout: boxes[1024*4] | labels[1024] | scores[1024] | confs[1024*21]
__global__ __launch_bounds__(64) void k_scan_gather(
    const unsigned long long* __restrict__ mask,
    const unsigned long long* __restrict__ vbits,
    const int* __restrict__ order, const float* __restrict__ ssc,
    const float* __restrict__ locs, const float* __restrict__ confs,
    const float* __restrict__ labelsF, float* __restrict__ out) {
  const int t = threadIdx.x;  // 0..63
  const int g = t >> 4, l = t & 15;
  unsigned long long supp = 0;   // lanes 0..15: suppressed bits, cols 64l..
  unsigned long long vw = (t < 16) ? vbits[t] : 0ull;
  unsigned long long mykeep = 0; // lane c: keep word of chunk c

  for (int c = 0; c < 16; ++c) {
    const int cb = c * 64;
    // intra-chunk row word for lane t (prefetch-friendly, indep of scan state)
    unsigned long long row = mask[(size_t)(cb + t) * 16 + c];
    unsigned long long vword = __shfl(vw, c);
    unsigned long long sword = __shfl(supp, c);
    bool valid_ok = ((vword >> t) & 1ull) && !((sword >> t) & 1ull);
    unsigned long long K = 0;
#pragma unroll
    for (int i = 0; i < 64; ++i) {
      bool ok = valid_ok && ((row & K) == 0ull);
      unsigned long long b = __ballot(ok);
      K |= b & (1ull << i);
    }
    if (t == c) mykeep = K;
    if (K) {
      // OR kept rows into global suppression vector (future chunks).
      // group g handles rows [16g,16g+16), lane-in-group l handles word l.
      unsigned long long part = 0;
#pragma unroll
      for (int ii = 0; ii < 16; ++ii) {
        int i = g * 16 + ii;
        unsigned long long m = mask[(size_t)(cb + i) * 16 + l];
        part |= (((K >> i) & 1ull) ? m : 0ull);
      }
      part |= __shfl_xor(part, 16);
      part |= __shfl_xor(part, 32);
      if (t < 16) supp |= part;
    }
  }

  // ---- fused gather: i = iter*64 + t, keep word = __shfl(mykeep, iter) ----
  for (int iter = 0; iter < 16; ++iter) {
    int i = iter * 64 + t;
    unsigned long long kw = __shfl(mykeep, iter);
    bool k = (kw >> t) & 1ull;
    int oi = order[i];
    float4 bx = k ? ((const float4*)locs)[oi]
                  : make_float4(-1.f, -1.f, -1.f, -1.f);
    ((float4*)out)[i] = bx;
    out[4096 + i] = k ? labelsF[oi] : 0.f;
    out[5120 + i] = k ? ssc[i] : -1.f;
    float* oc = out + 6144 + (size_t)i * 21;
    const float* cc = confs + (size_t)oi * 21;
#pragma unroll
    for (int c = 0; c < 21; ++c) oc[c] = k ? cc[c] : -1.f;
  }
}

// ============================================================================
extern "C" void kernel_launch(void* const* d_in, const int* in_sizes, int n_in,
                              void* d_out, int out_size, void* d_ws, size_t ws_size,
                              hipStream_t stream) {
  const float* x    = (const float*)d_in[0] + (size_t)7 * 3 * 512 * 512;  // image 7
  const float* w1   = (const float*)d_in[1];
  const float* b1   = (const float*)d_in[2];
  const float* w2   = (const float*)d_in[3];
  const float* b2   = (const float*)d_in[4];
  const float* w3   = (const float*)d_in[5];
  const float* b3   = (const float*)d_in[6];
  const float* w4   = (const float*)d_in[7];
  const float* b4   = (const float*)d_in[8];
  const float* regw = (const float*)d_in[9];
  const float* regb = (const float*)d_in[10];
  const float* clsw = (const float*)d_in[11];
  const float* clsb = (const float*)d_in[12];
  float* out = (float*)d_out;
  char* ws = (char*)d_ws;

  // region A (0..16.8MB): h1, then part4 + h4t
  float* h1    = (float*)(ws + 0);          // 16.8MB  (dead after conv2)
  float* part4 = (float*)(ws + 0);          // 4MB     (dead after combine)
  float* h4t   = (float*)(ws + 9437184);    // 1MB
  float* h2    = (float*)(ws + 16777216);   // 8.4MB   (dead after conv3)
  float* h3    = (float*)(ws + 25165824);   // 4.2MB
  float* wr2   = (float*)(ws + 29360128);
  float* wr3   = (float*)(ws + 29655040);
  float* wr4   = (float*)(ws + 30834688);
  float* wh    = (float*)(ws + 33193984);
  float* locs  = (float*)(ws + 33424384);
  float* confs = (float*)(ws + 33440768);
  float* scores  = (float*)(ws + 33526784);
  float* labelsF = (float*)(ws + 33530880);
  int*   order   = (int*)  (ws + 33534976);
  float* ssc     = (float*)(ws + 33539072);
  float* bsrt    = (float*)(ws + 33543168);
  unsigned long long* mask  = (unsigned long long*)(ws + 33559552);
  unsigned long long* vbits = (unsigned long long*)(ws + 33690624);

  k_repack_all<<<3969, 256, 0, stream>>>(w2, w3, w4, regw, clsw,
                                         wr2, wr3, wr4, wh);

  k_conv1<<<dim3(16, 16, 4), dim3(16, 16), 0, stream>>>(x, w1, b1, h1);

  // conv2: 64->128, 256->128. 256 sp x 8 co = 2048 blocks, NST=4, LDS ~21KB
  conv_s2<64, 128, 256, 256, 4, 16, 4, 16, 1, 19>
      <<<dim3(256, 8, 1), 256, 0, stream>>>(h1, wr2, b2, h2);
  // conv3: 128->256, 128->64. KSPLIT=1 (R0 numerics). 64 sp x 16 co = 1024
  conv_s2<128, 256, 128, 128, 8, 8, 4, 16, 1, 9>
      <<<dim3(64, 16, 1), 256, 0, stream>>>(h2, wr3, b3, h3);
  // conv4: 256->256, 64->32. KSPLIT=4, 64-ci chunks (R0 numerics). 1024 blocks
  conv_s2<256, 256, 64, 64, 8, 8, 4, 16, 4, 9>
      <<<dim3(16, 16, 4), 256, 0, stream>>>(h3, wr4, (const float*)nullptr, part4);
  k_combine<<<256, 256, 0, stream>>>(part4, b4, h4t);

  k_head<<<1024, 256, 0, stream>>>(h4t, wh, regb, clsb, locs, confs, scores, labelsF);

  k_sort<<<1, 512, 0, stream>>>(scores, locs, order, ssc, bsrt, vbits);
  k_mask<<<64, 256, 0, stream>>>(bsrt, mask);
  k_scan_gather<<<1, 64, 0, stream>>>(mask, vbits, order, ssc, locs, confs,
                                      labelsF, out);
}

// Round 7
// 404.741 us; speedup vs baseline: 2.1291x; 1.1737x over previous
//
#include <hip/hip_runtime.h>
#include <cstdint>
#include <cstddef>

// ============================================================================
// SSD forward (image 7 only) + NMS, all fp32.
// R6: NMS scan -> parallel fixpoint certification (exact greedy):
//   DEAD(i) if exists j<i, A[i][j], j KEPT;  KEPT(i) if all j<i A[i][j] DEAD.
// Iterate to fixpoint (provably terminates; each round certifies the smallest
// unknown). 1024 threads, row i in registers (16xu64), KEEP/DEAD bit-vectors
// in LDS, per-wave ballot writeback (wave w owns word w). Fused gather over
// 16 waves. Bit-identical keep decisions to R5's serial scan.
// Convs/head/sort unchanged from R5 (passed, absmax 9.8e-4).
// ============================================================================

// ---------------- fused weight repack ----------------------------------------
// wr[(ci*9+tap)*COUT+co] from w[co][ci][3][3]; head: wh[(tap*25+o)*256+ci]
__global__ __launch_bounds__(256) void k_repack_all(
    const float* __restrict__ w2, const float* __restrict__ w3,
    const float* __restrict__ w4, const float* __restrict__ regw,
    const float* __restrict__ clsw, float* __restrict__ wr2,
    float* __restrict__ wr3, float* __restrict__ wr4, float* __restrict__ wh) {
  int idx = blockIdx.x * 256 + threadIdx.x;
  if (idx < 73728) {  // conv2: CIN=64 COUT=128
    int co = idx % 128, r = idx / 128, ci = r / 9, tap = r % 9;
    wr2[idx] = w2[(co * 64 + ci) * 9 + tap];
  } else if (idx < 73728 + 294912) {  // conv3: CIN=128 COUT=256
    int i = idx - 73728;
    int co = i % 256, r = i / 256, ci = r / 9, tap = r % 9;
    wr3[i] = w3[(co * 128 + ci) * 9 + tap];
  } else if (idx < 73728 + 294912 + 589824) {  // conv4: CIN=256 COUT=256
    int i = idx - (73728 + 294912);
    int co = i % 256, r = i / 256, ci = r / 9, tap = r % 9;
    wr4[i] = w4[(co * 256 + ci) * 9 + tap];
  } else if (idx < 73728 + 294912 + 589824 + 57600) {  // head
    int i = idx - (73728 + 294912 + 589824);
    int ci = i & 255, r = i >> 8, tap = r / 25, o = r % 25;
    wh[i] = (o < 4) ? regw[(o * 256 + ci) * 9 + tap]
                    : clsw[((o - 4) * 256 + ci) * 9 + tap];
  }
}

// ---------------- conv1: 3->64, 512->256, stride 2, co-split by blockIdx.z ---
__global__ __launch_bounds__(256) void k_conv1(const float* __restrict__ x,
                                               const float* __restrict__ w,
                                               const float* __restrict__ b,
                                               float* __restrict__ out) {
  __shared__ float in_t[3][33][33];
  const int tx = threadIdx.x, ty = threadIdx.y;
  const int tid = ty * 16 + tx;
  const int ox0 = blockIdx.x * 16, oy0 = blockIdx.y * 16;
  const int co0 = blockIdx.z * 16;
  for (int idx = tid; idx < 3 * 33 * 33; idx += 256) {
    int ci = idx / 1089, rem = idx % 1089;
    int r = rem / 33, c = rem % 33;
    int iy = oy0 * 2 + r, ix = ox0 * 2 + c;
    float v = 0.f;
    if (iy < 512 && ix < 512) v = x[(size_t)ci * 262144 + iy * 512 + ix];
    in_t[ci][r][c] = v;
  }
  __syncthreads();
  float rin[27];
#pragma unroll
  for (int ci = 0; ci < 3; ++ci)
#pragma unroll
    for (int kh = 0; kh < 3; ++kh)
#pragma unroll
      for (int kw = 0; kw < 3; ++kw)
        rin[ci * 9 + kh * 3 + kw] = in_t[ci][2 * ty + kh][2 * tx + kw];
  const int oy = oy0 + ty, ox = ox0 + tx;
  for (int co = co0; co < co0 + 16; ++co) {  // co uniform -> weights via s_load
    float a = 0.f;
#pragma unroll
    for (int k = 0; k < 27; ++k) a = fmaf(w[co * 27 + k], rin[k], a);
    out[(size_t)co * 65536 + oy * 256 + ox] = fmaxf(a + b[co], 0.f);
  }
}

// ---------------- generic stride-2 3x3 conv, SAME(pad lo 0 hi 1) -------------
// 256 thr = 4 co-groups (wave-uniform cout via readfirstlane) x 64 lanes.
// Lane lp -> output position (py=lp/SW, px=lp%SW); SH*SW == 64.
// LDS: EV plane (even input cols) + OD plane (odd input cols), row stride
// PADW -> stride-2 conv reads become stride-1. Staging loads float2 pairs.
// Per-output accumulation order: (ci,kh,kw) lexicographic — matches R0.
template <int CIN, int COUT, int HIN, int WIN, int SH, int SW, int COPT,
          int CIT, int KSPLIT, int PADW>
__global__ __launch_bounds__(256) void conv_s2(const float* __restrict__ in,
                                               const float* __restrict__ wr,
                                               const float* __restrict__ bias,
                                               float* __restrict__ out) {
  constexpr int HOUT = HIN / 2, WOUT = WIN / 2;
  constexpr int IH = SH * 2 + 1, IW = SW * 2 + 1, IW2 = (IW + 1) / 2;
  constexpr int COT = 4 * COPT;
  constexpr int ODOFF = CIT * IH * PADW;
  constexpr int TOT2 = CIT * IH * IW2;
  static_assert(SH * SW == 64, "one position per lane");
  __shared__ float lds[2 * ODOFF];

  const int tid = threadIdx.x;
  const int gu  = __builtin_amdgcn_readfirstlane(tid >> 6);
  const int lp  = tid & 63;
  const int py  = lp / SW, px = lp % SW;

  constexpr int ntx = WOUT / SW;
  const int bx = blockIdx.x % ntx, by = blockIdx.x / ntx;
  const int ox0 = bx * SW, oy0 = by * SH;
  const int co_blk = blockIdx.y * COT;
  const int cobase = co_blk + gu * COPT;
  const int ci_begin = (KSPLIT > 1) ? blockIdx.z * (CIN / KSPLIT) : 0;
  constexpr int NST = (CIN / KSPLIT) / CIT;

  float acc[COPT] = {};

  for (int st = 0; st < NST; ++st) {
    const int cib = ci_begin + st * CIT;
    if (st) __syncthreads();   // protect previous stage's reads
    // ---- staging: global float2 pairs -> de-interleaved LDS planes ----
    for (int idx = tid; idx < TOT2; idx += 256) {
      int ci = idx / (IH * IW2), rem = idx % (IH * IW2);
      int r = rem / IW2, c2 = rem % IW2;
      int c = 2 * c2;
      int iy = oy0 * 2 + r, ix = ox0 * 2 + c;
      float v0 = 0.f, v1 = 0.f;
      const float* src = in + (size_t)(cib + ci) * HIN * WIN;
      if (iy < HIN) {
        if ((c + 1 < IW) && (ix + 1 < WIN)) {
          float2 t = *(const float2*)(src + (size_t)iy * WIN + ix);
          v0 = t.x; v1 = t.y;
        } else if (ix < WIN) {
          v0 = src[(size_t)iy * WIN + ix];
        }
      }
      int slot = (ci * IH + r) * PADW + c2;
      lds[slot] = v0;           // even col plane
      lds[ODOFF + slot] = v1;   // odd col plane
    }
    __syncthreads();
    // ---- compute ----
#pragma unroll 2
    for (int ci = 0; ci < CIT; ++ci) {
#pragma unroll
      for (int kh = 0; kh < 3; ++kh) {
        const int row = (ci * IH + 2 * py + kh) * PADW;
        float e0 = lds[row + px];          // kw=0 : col 2px
        float o0 = lds[ODOFF + row + px];  // kw=1 : col 2px+1
        float e1 = lds[row + px + 1];      // kw=2 : col 2px+2
        const float* wp =
            wr + ((size_t)(cib + ci) * 9 + kh * 3) * COUT + cobase;
#pragma unroll
        for (int c = 0; c < COPT; ++c) acc[c] = fmaf(e0, wp[c], acc[c]);
#pragma unroll
        for (int c = 0; c < COPT; ++c) acc[c] = fmaf(o0, wp[COUT + c], acc[c]);
#pragma unroll
        for (int c = 0; c < COPT; ++c) acc[c] = fmaf(e1, wp[2 * COUT + c], acc[c]);
      }
    }
  }

  const int oy = oy0 + py, ox = ox0 + px;
#pragma unroll
  for (int c = 0; c < COPT; ++c) {
    int co = cobase + c;
    if constexpr (KSPLIT > 1) {
      out[((size_t)blockIdx.z * COUT + co) * (HOUT * WOUT) + oy * WOUT + ox] =
          acc[c];
    } else {
      out[(size_t)co * (HOUT * WOUT) + oy * WOUT + ox] =
          fmaxf(acc[c] + bias[co], 0.f);
    }
  }
}

// ---------------- combine conv4 K-split partials + bias + relu, write NHWC ---
// EXACT R0 semantics: v = ((p0+p1)+p2)+p3; out = max(v+b, 0)
__global__ __launch_bounds__(256) void k_combine(const float* __restrict__ part,
                                                 const float* __restrict__ b,
                                                 float* __restrict__ h4t) {
  int co = blockIdx.x;  // 0..255
  float bb = b[co];
  for (int k2 = 0; k2 < 4; ++k2) {
    int pos = threadIdx.x + k2 * 256;
    float v = part[(size_t)(0 * 256 + co) * 1024 + pos] +
              part[(size_t)(1 * 256 + co) * 1024 + pos] +
              part[(size_t)(2 * 256 + co) * 1024 + pos] +
              part[(size_t)(3 * 256 + co) * 1024 + pos];
    h4t[(size_t)pos * 256 + co] = fmaxf(v + bb, 0.f);
  }
}

// ---------------- head: reg(4)+cls(21) stride-1 conv + softmax/max/argmax ----
__global__ __launch_bounds__(256) void k_head(const float* __restrict__ h4t,
                                              const float* __restrict__ wh,
                                              const float* __restrict__ regb,
                                              const float* __restrict__ clsb,
                                              float* __restrict__ locs,
                                              float* __restrict__ confs,
                                              float* __restrict__ scores,
                                              float* __restrict__ labelsF) {
  const int pos = blockIdx.x;
  const int py = pos >> 5, px = pos & 31;
  const int t = threadIdx.x;
  float part[25] = {};
#pragma unroll
  for (int kh = 0; kh < 3; ++kh) {
    int iy = py + kh - 1;
    if (iy < 0 || iy > 31) continue;  // block-uniform
#pragma unroll
    for (int kw = 0; kw < 3; ++kw) {
      int ix = px + kw - 1;
      if (ix < 0 || ix > 31) continue;
      int tap = kh * 3 + kw;
      float v = h4t[(size_t)(iy * 32 + ix) * 256 + t];
      const float* wp = wh + (size_t)tap * 25 * 256 + t;
#pragma unroll
      for (int o = 0; o < 25; ++o)
        part[o] = fmaf(v, wp[(size_t)o * 256], part[o]);
    }
  }
#pragma unroll
  for (int o = 0; o < 25; ++o) {
#pragma unroll
    for (int d = 1; d < 64; d <<= 1) part[o] += __shfl_xor(part[o], d);
  }
  __shared__ float red[4][25];
  __shared__ float yv[25];
  const int wv = t >> 6, ln = t & 63;
  if (ln == 0) {
#pragma unroll
    for (int o = 0; o < 25; ++o) red[wv][o] = part[o];
  }
  __syncthreads();
  if (t < 25) {
    float y = red[0][t] + red[1][t] + red[2][t] + red[3][t];
    y += (t < 4) ? regb[t] : clsb[t - 4];
    if (t < 4) locs[(size_t)pos * 4 + t] = y;
    else       confs[(size_t)pos * 21 + (t - 4)] = y;
    yv[t] = y;
  }
  __syncthreads();
  if (t == 0) {
    float m = yv[4];
    int lab = 0;
    for (int j = 1; j < 21; ++j)
      if (yv[4 + j] > m) { m = yv[4 + j]; lab = j; }  // first-max semantics
    float s = 0.f;
    for (int j = 0; j < 21; ++j) s += expf(yv[4 + j] - m);
    scores[pos] = 1.f / s;   // max softmax prob
    labelsF[pos] = (float)lab;
  }
}

// ---------------- stable descending bitonic sort of 1024 scores --------------
__global__ __launch_bounds__(512) void k_sort(const float* __restrict__ scores,
                                              const float* __restrict__ locs,
                                              int* __restrict__ order,
                                              float* __restrict__ ssc,
                                              float* __restrict__ bsrt,
                                              unsigned long long* __restrict__ vbits) {
  __shared__ float sk[1024];
  __shared__ int   si[1024];
  const int t = threadIdx.x;
  sk[t] = scores[t];           si[t] = t;
  sk[t + 512] = scores[t + 512]; si[t + 512] = t + 512;
  for (int k = 2; k <= 1024; k <<= 1) {
    for (int j = k >> 1; j > 0; j >>= 1) {
      __syncthreads();
      int i1 = ((t / j) * (2 * j)) + (t % j);
      int i2 = i1 + j;
      bool up = (i1 & k) == 0;
      float sa = sk[i1], sb = sk[i2];
      int ia = si[i1], ib = si[i2];
      bool b_before_a = (sb > sa) || (sb == sa && ib < ia);
      bool a_before_b = (sa > sb) || (sa == sb && ia < ib);
      bool sw = up ? b_before_a : a_before_b;
      if (sw) { sk[i1] = sb; sk[i2] = sa; si[i1] = ib; si[i2] = ia; }
    }
  }
  __syncthreads();
  for (int i = t; i < 1024; i += 512) {
    int oi = si[i];
    order[i] = oi;
    ssc[i] = sk[i];
    ((float4*)bsrt)[i] = ((const float4*)locs)[oi];
  }
  if (t < 16) {  // validity bits (score > SCORE_THR), sorted order
    unsigned long long w = 0;
    for (int b2 = 0; b2 < 64; ++b2)
      if (sk[t * 64 + b2] > 0.04f) w |= (1ull << b2);
    vbits[t] = w;
  }
}

// ---------------- pairwise IoU suppression bitmask (1024x1024 bits) ----------
__global__ __launch_bounds__(256) void k_mask(const float* __restrict__ bsrt,
                                              unsigned long long* __restrict__ mask) {
  __shared__ float4 sb[1024];
  const int t = threadIdx.x;
  for (int idx = t; idx < 1024; idx += 256)
    sb[idx] = ((const float4*)bsrt)[idx];
  __syncthreads();
  const int i = blockIdx.x * 16 + (t & 15);
  const int w = t >> 4;
  float4 bi = sb[i];
  float ai = (bi.z - bi.x) * (bi.w - bi.y);
  unsigned long long bits = 0;
  for (int jj = 0; jj < 64; ++jj) {
    float4 bj = sb[w * 64 + jj];
    float aj = (bj.z - bj.x) * (bj.w - bj.y);
    float ltx = fmaxf(bi.x, bj.x), lty = fmaxf(bi.y, bj.y);
    float rbx = fminf(bi.z, bj.z), rby = fminf(bi.w, bj.w);
    float inter = fmaxf(rbx - ltx, 0.f) * fmaxf(rby - lty, 0.f);
    float uni = ai + aj - inter;
    float iou = inter / (uni + 1e-9f);
    if (iou > 0.5f) bits |= (1ull << jj);
  }
  mask[(size_t)i * 16 + w] = bits;
}

// ---------------- parallel fixpoint greedy NMS + fused gather ----------------
// 1024 threads (16 waves). Thread i owns sorted box i; its lower-triangle
// suppression row (j<i) lives in 16 u64 registers. LDS KEEP/DEAD bit-vectors.
// Round: i DEAD if row&KEEP != 0; i KEPT if row&~DEAD == 0 (and valid).
// Wave w owns word w -> lane-0 ballot writeback, no atomics on the vectors.
// Fixpoint == greedy keep set exactly (each round certifies the smallest
// uncertified index, so it terminates).
// layout: boxes[1024*4] | labels[1024] | scores[1024] | confs[1024*21]
__global__ __launch_bounds__(1024) void k_nms_gather(
    const unsigned long long* __restrict__ mask,
    const unsigned long long* __restrict__ vbits,
    const int* __restrict__ order, const float* __restrict__ ssc,
    const float* __restrict__ locs, const float* __restrict__ confs,
    const float* __restrict__ labelsF, float* __restrict__ out) {
  __shared__ unsigned long long KEEP[16], DEAD[16];
  __shared__ int ncert;
  const int i = threadIdx.x;        // box index (sorted order)
  const int w = i >> 6, l = i & 63; // wave, lane

  // row restricted to j<i
  unsigned long long R[16];
#pragma unroll
  for (int k = 0; k < 16; ++k) {
    unsigned long long m = 0;
    if (k < w) m = mask[(size_t)i * 16 + k];
    else if (k == w && l) m = mask[(size_t)i * 16 + k] & ((1ull << l) - 1ull);
    R[k] = m;
  }
  const bool valid = (vbits[w] >> l) & 1ull;

  if (i < 16) { KEEP[i] = 0ull; DEAD[i] = 0ull; }
  if (i == 0) ncert = 0;
  __syncthreads();

  int status = 0;  // 0 unknown, 1 kept, 2 dead
  for (;;) {
    // ---- snapshot-read phase ----
    unsigned long long s = 0, p = 0;
    if (status == 0) {
#pragma unroll
      for (int k = 0; k < 16; ++k) {
        unsigned long long K_ = KEEP[k], D_ = DEAD[k];
        s |= R[k] & K_;
        p |= R[k] & ~D_;
      }
    }
    __syncthreads();  // all reads done before any write
    // ---- certify phase ----
    bool newKeep = false, newDead = false;
    if (status == 0) {
      if (!valid)      { status = 2; newDead = true; }
      else if (s)      { status = 2; newDead = true; }
      else if (!p)     { status = 1; newKeep = true; }
    }
    unsigned long long bk = __ballot(newKeep);
    unsigned long long bd = __ballot(newDead);
    if (l == 0) {
      if (bk) KEEP[w] |= bk;
      if (bd) DEAD[w] |= bd;
      int n = __popcll(bk) + __popcll(bd);
      if (n) atomicAdd(&ncert, n);
    }
    __syncthreads();
    if (ncert >= 1024) break;
  }

  // ---- fused gather (thread i -> output row i) ----
  const bool kp = (status == 1);
  const int oi = order[i];
  float4 bx = kp ? ((const float4*)locs)[oi]
                 : make_float4(-1.f, -1.f, -1.f, -1.f);
  ((float4*)out)[i] = bx;
  out[4096 + i] = kp ? labelsF[oi] : 0.f;
  out[5120 + i] = kp ? ssc[i] : -1.f;
  float* oc = out + 6144 + (size_t)i * 21;
  const float* cc = confs + (size_t)oi * 21;
#pragma unroll
  for (int c = 0; c < 21; ++c) oc[c] = kp ? cc[c] : -1.f;
}

// ============================================================================
extern "C" void kernel_launch(void* const* d_in, const int* in_sizes, int n_in,
                              void* d_out, int out_size, void* d_ws, size_t ws_size,
                              hipStream_t stream) {
  const float* x    = (const float*)d_in[0] + (size_t)7 * 3 * 512 * 512;  // image 7
  const float* w1   = (const float*)d_in[1];
  const float* b1   = (const float*)d_in[2];
  const float* w2   = (const float*)d_in[3];
  const float* b2   = (const float*)d_in[4];
  const float* w3   = (const float*)d_in[5];
  const float* b3   = (const float*)d_in[6];
  const float* w4   = (const float*)d_in[7];
  const float* b4   = (const float*)d_in[8];
  const float* regw = (const float*)d_in[9];
  const float* regb = (const float*)d_in[10];
  const float* clsw = (const float*)d_in[11];
  const float* clsb = (const float*)d_in[12];
  float* out = (float*)d_out;
  char* ws = (char*)d_ws;

  // region A (0..16.8MB): h1, then part4 + h4t
  float* h1    = (float*)(ws + 0);          // 16.8MB  (dead after conv2)
  float* part4 = (float*)(ws + 0);          // 4MB     (dead after combine)
  float* h4t   = (float*)(ws + 9437184);    // 1MB
  float* h2    = (float*)(ws + 16777216);   // 8.4MB   (dead after conv3)
  float* h3    = (float*)(ws + 25165824);   // 4.2MB
  float* wr2   = (float*)(ws + 29360128);
  float* wr3   = (float*)(ws + 29655040);
  float* wr4   = (float*)(ws + 30834688);
  float* wh    = (float*)(ws + 33193984);
  float* locs  = (float*)(ws + 33424384);
  float* confs = (float*)(ws + 33440768);
  float* scores  = (float*)(ws + 33526784);
  float* labelsF = (float*)(ws + 33530880);
  int*   order   = (int*)  (ws + 33534976);
  float* ssc     = (float*)(ws + 33539072);
  float* bsrt    = (float*)(ws + 33543168);
  unsigned long long* mask  = (unsigned long long*)(ws + 33559552);
  unsigned long long* vbits = (unsigned long long*)(ws + 33690624);

  k_repack_all<<<3969, 256, 0, stream>>>(w2, w3, w4, regw, clsw,
                                         wr2, wr3, wr4, wh);

  k_conv1<<<dim3(16, 16, 4), dim3(16, 16), 0, stream>>>(x, w1, b1, h1);

  // conv2: 64->128, 256->128. 256 sp x 8 co = 2048 blocks, NST=4, LDS ~21KB
  conv_s2<64, 128, 256, 256, 4, 16, 4, 16, 1, 19>
      <<<dim3(256, 8, 1), 256, 0, stream>>>(h1, wr2, b2, h2);
  // conv3: 128->256, 128->64. KSPLIT=1 (R0 numerics). 64 sp x 16 co = 1024
  conv_s2<128, 256, 128, 128, 8, 8, 4, 16, 1, 9>
      <<<dim3(64, 16, 1), 256, 0, stream>>>(h2, wr3, b3, h3);
  // conv4: 256->256, 64->32. KSPLIT=4, 64-ci chunks (R0 numerics). 1024 blocks
  conv_s2<256, 256, 64, 64, 8, 8, 4, 16, 4, 9>
      <<<dim3(16, 16, 4), 256, 0, stream>>>(h3, wr4, (const float*)nullptr, part4);
  k_combine<<<256, 256, 0, stream>>>(part4, b4, h4t);

  k_head<<<1024, 256, 0, stream>>>(h4t, wh, regb, clsb, locs, confs, scores, labelsF);

  k_sort<<<1, 512, 0, stream>>>(scores, locs, order, ssc, bsrt, vbits);
  k_mask<<<64, 256, 0, stream>>>(bsrt, mask);
  k_nms_gather<<<1, 1024, 0, stream>>>(mask, vbits, order, ssc, locs, confs,
                                       labelsF, out);
}

// Round 8
// 400.388 us; speedup vs baseline: 2.1523x; 1.0109x over previous
//
#include <hip/hip_runtime.h>
#include <cstdint>
#include <cstddef>

// ============================================================================
// SSD forward (image 7 only) + NMS, all fp32.
// R7: conv_s2 LDS-issue-bound fix. Row-interleaved LDS layout
// [EV(SW+1)|OD(SW)|pad] (ROWW words/row) puts all 9 taps of a ci at ONE
// vaddr + const offsets -> ds_read2_b32 merging (9 vals ~5 instr). ROWW
// tuned (36 for SW=16, 18 for SW=8) so lanes hit every bank exactly 2x
// (free). conv2 COPT 4->8 halves its total LDS traffic (VALU-bound now).
// FMA order per output: tap 0..8 (kh,kw) lexicographic, ci ascending —
// exact R0 numerics (passed 5x). NMS fixpoint + rest unchanged from R6.
// ============================================================================

// ---------------- fused weight repack ----------------------------------------
// wr[(ci*9+tap)*COUT+co] from w[co][ci][3][3]; head: wh[(tap*25+o)*256+ci]
__global__ __launch_bounds__(256) void k_repack_all(
    const float* __restrict__ w2, const float* __restrict__ w3,
    const float* __restrict__ w4, const float* __restrict__ regw,
    const float* __restrict__ clsw, float* __restrict__ wr2,
    float* __restrict__ wr3, float* __restrict__ wr4, float* __restrict__ wh) {
  int idx = blockIdx.x * 256 + threadIdx.x;
  if (idx < 73728) {  // conv2: CIN=64 COUT=128
    int co = idx % 128, r = idx / 128, ci = r / 9, tap = r % 9;
    wr2[idx] = w2[(co * 64 + ci) * 9 + tap];
  } else if (idx < 73728 + 294912) {  // conv3: CIN=128 COUT=256
    int i = idx - 73728;
    int co = i % 256, r = i / 256, ci = r / 9, tap = r % 9;
    wr3[i] = w3[(co * 128 + ci) * 9 + tap];
  } else if (idx < 73728 + 294912 + 589824) {  // conv4: CIN=256 COUT=256
    int i = idx - (73728 + 294912);
    int co = i % 256, r = i / 256, ci = r / 9, tap = r % 9;
    wr4[i] = w4[(co * 256 + ci) * 9 + tap];
  } else if (idx < 73728 + 294912 + 589824 + 57600) {  // head
    int i = idx - (73728 + 294912 + 589824);
    int ci = i & 255, r = i >> 8, tap = r / 25, o = r % 25;
    wh[i] = (o < 4) ? regw[(o * 256 + ci) * 9 + tap]
                    : clsw[((o - 4) * 256 + ci) * 9 + tap];
  }
}

// ---------------- conv1: 3->64, 512->256, stride 2, co-split by blockIdx.z ---
__global__ __launch_bounds__(256) void k_conv1(const float* __restrict__ x,
                                               const float* __restrict__ w,
                                               const float* __restrict__ b,
                                               float* __restrict__ out) {
  __shared__ float in_t[3][33][33];
  const int tx = threadIdx.x, ty = threadIdx.y;
  const int tid = ty * 16 + tx;
  const int ox0 = blockIdx.x * 16, oy0 = blockIdx.y * 16;
  const int co0 = blockIdx.z * 16;
  for (int idx = tid; idx < 3 * 33 * 33; idx += 256) {
    int ci = idx / 1089, rem = idx % 1089;
    int r = rem / 33, c = rem % 33;
    int iy = oy0 * 2 + r, ix = ox0 * 2 + c;
    float v = 0.f;
    if (iy < 512 && ix < 512) v = x[(size_t)ci * 262144 + iy * 512 + ix];
    in_t[ci][r][c] = v;
  }
  __syncthreads();
  float rin[27];
#pragma unroll
  for (int ci = 0; ci < 3; ++ci)
#pragma unroll
    for (int kh = 0; kh < 3; ++kh)
#pragma unroll
      for (int kw = 0; kw < 3; ++kw)
        rin[ci * 9 + kh * 3 + kw] = in_t[ci][2 * ty + kh][2 * tx + kw];
  const int oy = oy0 + ty, ox = ox0 + tx;
  for (int co = co0; co < co0 + 16; ++co) {  // co uniform -> weights via s_load
    float a = 0.f;
#pragma unroll
    for (int k = 0; k < 27; ++k) a = fmaf(w[co * 27 + k], rin[k], a);
    out[(size_t)co * 65536 + oy * 256 + ox] = fmaxf(a + b[co], 0.f);
  }
}

// ---------------- generic stride-2 3x3 conv, SAME(pad lo 0 hi 1) -------------
// 256 thr = 4 co-groups (wave-uniform cout via readfirstlane) x 64 lanes.
// Lane lp -> output position (py=lp/SW, px=lp%SW); SH*SW == 64.
// LDS row layout: [EV: SW+1 even cols | OD: SW odd cols | pad] = ROWW words.
// All 9 taps of one ci: single vaddr + const offsets -> ds_read2 merging.
// ROWW chosen so (2*ROWW*py+px) mod 32 covers each bank exactly 2x (free).
// Per-output accumulation order: tap 0..8 = (kh,kw) lexicographic, ci asc.
template <int CIN, int COUT, int HIN, int WIN, int SH, int SW, int COPT,
          int CIT, int KSPLIT, int ROWW>
__global__ __launch_bounds__(256) void conv_s2(const float* __restrict__ in,
                                               const float* __restrict__ wr,
                                               const float* __restrict__ bias,
                                               float* __restrict__ out) {
  constexpr int HOUT = HIN / 2, WOUT = WIN / 2;
  constexpr int IH = SH * 2 + 1, IW = SW * 2 + 1;
  constexpr int EVW = SW + 1;
  constexpr int COT = 4 * COPT;
  constexpr int NPAIR = CIT * IH * EVW;
  static_assert(SH * SW == 64, "one position per lane");
  static_assert(EVW + SW < ROWW + 1, "pad slot fits");
  __shared__ float lds[CIT * IH * ROWW];

  const int tid = threadIdx.x;
  const int gu  = __builtin_amdgcn_readfirstlane(tid >> 6);
  const int lp  = tid & 63;
  const int py  = lp / SW, px = lp % SW;

  constexpr int ntx = WOUT / SW;
  const int bx = blockIdx.x % ntx, by = blockIdx.x / ntx;
  const int ox0 = bx * SW, oy0 = by * SH;
  const int co_blk = blockIdx.y * COT;
  const int cobase = co_blk + gu * COPT;
  const int ci_begin = (KSPLIT > 1) ? blockIdx.z * (CIN / KSPLIT) : 0;
  constexpr int NST = (CIN / KSPLIT) / CIT;

  float acc[COPT] = {};

  for (int st = 0; st < NST; ++st) {
    const int cib = ci_begin + st * CIT;
    if (st) __syncthreads();   // protect previous stage's reads
    // ---- staging: global float2 pairs -> interleaved EV|OD row layout ----
    for (int idx = tid; idx < NPAIR; idx += 256) {
      int ci = idx / (IH * EVW), rem = idx % (IH * EVW);
      int r = rem / EVW, c2 = rem % EVW;
      int iy = oy0 * 2 + r, ix = ox0 * 2 + 2 * c2;
      float v0 = 0.f, v1 = 0.f;
      const float* src = in + (size_t)(cib + ci) * HIN * WIN;
      if (iy < HIN) {
        if ((2 * c2 + 1 < IW) && (ix + 1 < WIN)) {
          float2 t = *(const float2*)(src + (size_t)iy * WIN + ix);
          v0 = t.x; v1 = t.y;
        } else if (ix < WIN) {
          v0 = src[(size_t)iy * WIN + ix];
        }
      }
      int rb = (ci * IH + r) * ROWW;
      lds[rb + c2] = v0;            // even col c2
      lds[rb + EVW + c2] = v1;      // odd col c2 (c2==SW -> pad slot)
    }
    __syncthreads();
    // ---- compute: 9 taps per ci from one base addr ----
#pragma unroll 2
    for (int ci = 0; ci < CIT; ++ci) {
      const int b0 = (ci * IH + 2 * py) * ROWW + px;
      float e00 = lds[b0];               // (kh0,kw0) col 2px
      float q0  = lds[b0 + EVW];         // (kh0,kw1) col 2px+1
      float e01 = lds[b0 + 1];           // (kh0,kw2) col 2px+2
      float e10 = lds[b0 + ROWW];
      float q1  = lds[b0 + ROWW + EVW];
      float e11 = lds[b0 + ROWW + 1];
      float e20 = lds[b0 + 2 * ROWW];
      float q2  = lds[b0 + 2 * ROWW + EVW];
      float e21 = lds[b0 + 2 * ROWW + 1];
      const float* wp = wr + (size_t)(cib + ci) * 9 * COUT + cobase;
#pragma unroll
      for (int c = 0; c < COPT; ++c) acc[c] = fmaf(e00, wp[c], acc[c]);
#pragma unroll
      for (int c = 0; c < COPT; ++c) acc[c] = fmaf(q0, wp[COUT + c], acc[c]);
#pragma unroll
      for (int c = 0; c < COPT; ++c) acc[c] = fmaf(e01, wp[2 * COUT + c], acc[c]);
#pragma unroll
      for (int c = 0; c < COPT; ++c) acc[c] = fmaf(e10, wp[3 * COUT + c], acc[c]);
#pragma unroll
      for (int c = 0; c < COPT; ++c) acc[c] = fmaf(q1, wp[4 * COUT + c], acc[c]);
#pragma unroll
      for (int c = 0; c < COPT; ++c) acc[c] = fmaf(e11, wp[5 * COUT + c], acc[c]);
#pragma unroll
      for (int c = 0; c < COPT; ++c) acc[c] = fmaf(e20, wp[6 * COUT + c], acc[c]);
#pragma unroll
      for (int c = 0; c < COPT; ++c) acc[c] = fmaf(q2, wp[7 * COUT + c], acc[c]);
#pragma unroll
      for (int c = 0; c < COPT; ++c) acc[c] = fmaf(e21, wp[8 * COUT + c], acc[c]);
    }
  }

  const int oy = oy0 + py, ox = ox0 + px;
#pragma unroll
  for (int c = 0; c < COPT; ++c) {
    int co = cobase + c;
    if constexpr (KSPLIT > 1) {
      out[((size_t)blockIdx.z * COUT + co) * (HOUT * WOUT) + oy * WOUT + ox] =
          acc[c];
    } else {
      out[(size_t)co * (HOUT * WOUT) + oy * WOUT + ox] =
          fmaxf(acc[c] + bias[co], 0.f);
    }
  }
}

// ---------------- combine conv4 K-split partials + bias + relu, write NHWC ---
// EXACT R0 semantics: v = ((p0+p1)+p2)+p3; out = max(v+b, 0)
__global__ __launch_bounds__(256) void k_combine(const float* __restrict__ part,
                                                 const float* __restrict__ b,
                                                 float* __restrict__ h4t) {
  int co = blockIdx.x;  // 0..255
  float bb = b[co];
  for (int k2 = 0; k2 < 4; ++k2) {
    int pos = threadIdx.x + k2 * 256;
    float v = part[(size_t)(0 * 256 + co) * 1024 + pos] +
              part[(size_t)(1 * 256 + co) * 1024 + pos] +
              part[(size_t)(2 * 256 + co) * 1024 + pos] +
              part[(size_t)(3 * 256 + co) * 1024 + pos];
    h4t[(size_t)pos * 256 + co] = fmaxf(v + bb, 0.f);
  }
}

// ---------------- head: reg(4)+cls(21) stride-1 conv + softmax/max/argmax ----
__global__ __launch_bounds__(256) void k_head(const float* __restrict__ h4t,
                                              const float* __restrict__ wh,
                                              const float* __restrict__ regb,
                                              const float* __restrict__ clsb,
                                              float* __restrict__ locs,
                                              float* __restrict__ confs,
                                              float* __restrict__ scores,
                                              float* __restrict__ labelsF) {
  const int pos = blockIdx.x;
  const int py = pos >> 5, px = pos & 31;
  const int t = threadIdx.x;
  float part[25] = {};
#pragma unroll
  for (int kh = 0; kh < 3; ++kh) {
    int iy = py + kh - 1;
    if (iy < 0 || iy > 31) continue;  // block-uniform
#pragma unroll
    for (int kw = 0; kw < 3; ++kw) {
      int ix = px + kw - 1;
      if (ix < 0 || ix > 31) continue;
      int tap = kh * 3 + kw;
      float v = h4t[(size_t)(iy * 32 + ix) * 256 + t];
      const float* wp = wh + (size_t)tap * 25 * 256 + t;
#pragma unroll
      for (int o = 0; o < 25; ++o)
        part[o] = fmaf(v, wp[(size_t)o * 256], part[o]);
    }
  }
#pragma unroll
  for (int o = 0; o < 25; ++o) {
#pragma unroll
    for (int d = 1; d < 64; d <<= 1) part[o] += __shfl_xor(part[o], d);
  }
  __shared__ float red[4][25];
  __shared__ float yv[25];
  const int wv = t >> 6, ln = t & 63;
  if (ln == 0) {
#pragma unroll
    for (int o = 0; o < 25; ++o) red[wv][o] = part[o];
  }
  __syncthreads();
  if (t < 25) {
    float y = red[0][t] + red[1][t] + red[2][t] + red[3][t];
    y += (t < 4) ? regb[t] : clsb[t - 4];
    if (t < 4) locs[(size_t)pos * 4 + t] = y;
    else       confs[(size_t)pos * 21 + (t - 4)] = y;
    yv[t] = y;
  }
  __syncthreads();
  if (t == 0) {
    float m = yv[4];
    int lab = 0;
    for (int j = 1; j < 21; ++j)
      if (yv[4 + j] > m) { m = yv[4 + j]; lab = j; }  // first-max semantics
    float s = 0.f;
    for (int j = 0; j < 21; ++j) s += expf(yv[4 + j] - m);
    scores[pos] = 1.f / s;   // max softmax prob
    labelsF[pos] = (float)lab;
  }
}

// ---------------- stable descending bitonic sort of 1024 scores --------------
__global__ __launch_bounds__(512) void k_sort(const float* __restrict__ scores,
                                              const float* __restrict__ locs,
                                              int* __restrict__ order,
                                              float* __restrict__ ssc,
                                              float* __restrict__ bsrt,
                                              unsigned long long* __restrict__ vbits) {
  __shared__ float sk[1024];
  __shared__ int   si[1024];
  const int t = threadIdx.x;
  sk[t] = scores[t];           si[t] = t;
  sk[t + 512] = scores[t + 512]; si[t + 512] = t + 512;
  for (int k = 2; k <= 1024; k <<= 1) {
    for (int j = k >> 1; j > 0; j >>= 1) {
      __syncthreads();
      int i1 = ((t / j) * (2 * j)) + (t % j);
      int i2 = i1 + j;
      bool up = (i1 & k) == 0;
      float sa = sk[i1], sb = sk[i2];
      int ia = si[i1], ib = si[i2];
      bool b_before_a = (sb > sa) || (sb == sa && ib < ia);
      bool a_before_b = (sa > sb) || (sa == sb && ia < ib);
      bool sw = up ? b_before_a : a_before_b;
      if (sw) { sk[i1] = sb; sk[i2] = sa; si[i1] = ib; si[i2] = ia; }
    }
  }
  __syncthreads();
  for (int i = t; i < 1024; i += 512) {
    int oi = si[i];
    order[i] = oi;
    ssc[i] = sk[i];
    ((float4*)bsrt)[i] = ((const float4*)locs)[oi];
  }
  if (t < 16) {  // validity bits (score > SCORE_THR), sorted order
    unsigned long long w = 0;
    for (int b2 = 0; b2 < 64; ++b2)
      if (sk[t * 64 + b2] > 0.04f) w |= (1ull << b2);
    vbits[t] = w;
  }
}

// ---------------- pairwise IoU suppression bitmask (1024x1024 bits) ----------
__global__ __launch_bounds__(256) void k_mask(const float* __restrict__ bsrt,
                                              unsigned long long* __restrict__ mask) {
  __shared__ float4 sb[1024];
  const int t = threadIdx.x;
  for (int idx = t; idx < 1024; idx += 256)
    sb[idx] = ((const float4*)bsrt)[idx];
  __syncthreads();
  const int i = blockIdx.x * 16 + (t & 15);
  const int w = t >> 4;
  float4 bi = sb[i];
  float ai = (bi.z - bi.x) * (bi.w - bi.y);
  unsigned long long bits = 0;
  for (int jj = 0; jj < 64; ++jj) {
    float4 bj = sb[w * 64 + jj];
    float aj = (bj.z - bj.x) * (bj.w - bj.y);
    float ltx = fmaxf(bi.x, bj.x), lty = fmaxf(bi.y, bj.y);
    float rbx = fminf(bi.z, bj.z), rby = fminf(bi.w, bj.w);
    float inter = fmaxf(rbx - ltx, 0.f) * fmaxf(rby - lty, 0.f);
    float uni = ai + aj - inter;
    float iou = inter / (uni + 1e-9f);
    if (iou > 0.5f) bits |= (1ull << jj);
  }
  mask[(size_t)i * 16 + w] = bits;
}

// ---------------- parallel fixpoint greedy NMS + fused gather ----------------
// 1024 threads (16 waves). Thread i owns sorted box i; lower-triangle row in
// 16 u64 registers. KEEP/DEAD bit-vectors in LDS; wave w owns word w (ballot
// writeback, no vector atomics). Fixpoint == exact greedy keep set.
// layout: boxes[1024*4] | labels[1024] | scores[1024] | confs[1024*21]
__global__ __launch_bounds__(1024) void k_nms_gather(
    const unsigned long long* __restrict__ mask,
    const unsigned long long* __restrict__ vbits,
    const int* __restrict__ order, const float* __restrict__ ssc,
    const float* __restrict__ locs, const float* __restrict__ confs,
    const float* __restrict__ labelsF, float* __restrict__ out) {
  __shared__ unsigned long long KEEP[16], DEAD[16];
  __shared__ int ncert;
  const int i = threadIdx.x;        // box index (sorted order)
  const int w = i >> 6, l = i & 63; // wave, lane

  // row restricted to j<i
  unsigned long long R[16];
#pragma unroll
  for (int k = 0; k < 16; ++k) {
    unsigned long long m = 0;
    if (k < w) m = mask[(size_t)i * 16 + k];
    else if (k == w && l) m = mask[(size_t)i * 16 + k] & ((1ull << l) - 1ull);
    R[k] = m;
  }
  const bool valid = (vbits[w] >> l) & 1ull;

  if (i < 16) { KEEP[i] = 0ull; DEAD[i] = 0ull; }
  if (i == 0) ncert = 0;
  __syncthreads();

  int status = 0;  // 0 unknown, 1 kept, 2 dead
  for (;;) {
    // ---- snapshot-read phase ----
    unsigned long long s = 0, p = 0;
    if (status == 0) {
#pragma unroll
      for (int k = 0; k < 16; ++k) {
        unsigned long long K_ = KEEP[k], D_ = DEAD[k];
        s |= R[k] & K_;
        p |= R[k] & ~D_;
      }
    }
    __syncthreads();  // all reads done before any write
    // ---- certify phase ----
    bool newKeep = false, newDead = false;
    if (status == 0) {
      if (!valid)      { status = 2; newDead = true; }
      else if (s)      { status = 2; newDead = true; }
      else if (!p)     { status = 1; newKeep = true; }
    }
    unsigned long long bk = __ballot(newKeep);
    unsigned long long bd = __ballot(newDead);
    if (l == 0) {
      if (bk) KEEP[w] |= bk;
      if (bd) DEAD[w] |= bd;
      int n = __popcll(bk) + __popcll(bd);
      if (n) atomicAdd(&ncert, n);
    }
    __syncthreads();
    if (ncert >= 1024) break;
  }

  // ---- fused gather (thread i -> output row i) ----
  const bool kp = (status == 1);
  const int oi = order[i];
  float4 bx = kp ? ((const float4*)locs)[oi]
                 : make_float4(-1.f, -1.f, -1.f, -1.f);
  ((float4*)out)[i] = bx;
  out[4096 + i] = kp ? labelsF[oi] : 0.f;
  out[5120 + i] = kp ? ssc[i] : -1.f;
  float* oc = out + 6144 + (size_t)i * 21;
  const float* cc = confs + (size_t)oi * 21;
#pragma unroll
  for (int c = 0; c < 21; ++c) oc[c] = kp ? cc[c] : -1.f;
}

// ============================================================================
extern "C" void kernel_launch(void* const* d_in, const int* in_sizes, int n_in,
                              void* d_out, int out_size, void* d_ws, size_t ws_size,
                              hipStream_t stream) {
  const float* x    = (const float*)d_in[0] + (size_t)7 * 3 * 512 * 512;  // image 7
  const float* w1   = (const float*)d_in[1];
  const float* b1   = (const float*)d_in[2];
  const float* w2   = (const float*)d_in[3];
  const float* b2   = (const float*)d_in[4];
  const float* w3   = (const float*)d_in[5];
  const float* b3   = (const float*)d_in[6];
  const float* w4   = (const float*)d_in[7];
  const float* b4   = (const float*)d_in[8];
  const float* regw = (const float*)d_in[9];
  const float* regb = (const float*)d_in[10];
  const float* clsw = (const float*)d_in[11];
  const float* clsb = (const float*)d_in[12];
  float* out = (float*)d_out;
  char* ws = (char*)d_ws;

  // region A (0..16.8MB): h1, then part4 + h4t
  float* h1    = (float*)(ws + 0);          // 16.8MB  (dead after conv2)
  float* part4 = (float*)(ws + 0);          // 4MB     (dead after combine)
  float* h4t   = (float*)(ws + 9437184);    // 1MB
  float* h2    = (float*)(ws + 16777216);   // 8.4MB   (dead after conv3)
  float* h3    = (float*)(ws + 25165824);   // 4.2MB
  float* wr2   = (float*)(ws + 29360128);
  float* wr3   = (float*)(ws + 29655040);
  float* wr4   = (float*)(ws + 30834688);
  float* wh    = (float*)(ws + 33193984);
  float* locs  = (float*)(ws + 33424384);
  float* confs = (float*)(ws + 33440768);
  float* scores  = (float*)(ws + 33526784);
  float* labelsF = (float*)(ws + 33530880);
  int*   order   = (int*)  (ws + 33534976);
  float* ssc     = (float*)(ws + 33539072);
  float* bsrt    = (float*)(ws + 33543168);
  unsigned long long* mask  = (unsigned long long*)(ws + 33559552);
  unsigned long long* vbits = (unsigned long long*)(ws + 33690624);

  k_repack_all<<<3969, 256, 0, stream>>>(w2, w3, w4, regw, clsw,
                                         wr2, wr3, wr4, wh);

  k_conv1<<<dim3(16, 16, 4), dim3(16, 16), 0, stream>>>(x, w1, b1, h1);

  // conv2: 64->128, 256->128. COPT=8 -> 256 sp x 4 co = 1024 blocks, ROWW=36
  conv_s2<64, 128, 256, 256, 4, 16, 8, 16, 1, 36>
      <<<dim3(256, 4, 1), 256, 0, stream>>>(h1, wr2, b2, h2);
  // conv3: 128->256, 128->64. KSPLIT=1 (R0 numerics). 64 sp x 16 co = 1024
  conv_s2<128, 256, 128, 128, 8, 8, 4, 16, 1, 18>
      <<<dim3(64, 16, 1), 256, 0, stream>>>(h2, wr3, b3, h3);
  // conv4: 256->256, 64->32. KSPLIT=4, 64-ci chunks (R0 numerics). 1024 blocks
  conv_s2<256, 256, 64, 64, 8, 8, 4, 16, 4, 18>
      <<<dim3(16, 16, 4), 256, 0, stream>>>(h3, wr4, (const float*)nullptr, part4);
  k_combine<<<256, 256, 0, stream>>>(part4, b4, h4t);

  k_head<<<1024, 256, 0, stream>>>(h4t, wh, regb, clsb, locs, confs, scores, labelsF);

  k_sort<<<1, 512, 0, stream>>>(scores, locs, order, ssc, bsrt, vbits);
  k_mask<<<64, 256, 0, stream>>>(bsrt, mask);
  k_nms_gather<<<1, 1024, 0, stream>>>(mask, vbits, order, ssc, locs, confs,
                                       labelsF, out);
}